// Round 7
// baseline (391.694 us; speedup 1.0000x reference)
//
#include <hip/hip_runtime.h>
#include <hip/hip_bf16.h>

#define SEQ 512
#define EMB 256
#define NHEAD 8
#define HD 32

using bf16x8 = __attribute__((ext_vector_type(8))) short;
using f32x4  = __attribute__((ext_vector_type(4))) float;

static __device__ __forceinline__ unsigned short f2bf(float x) {
    union { float f; unsigned int u; } v; v.f = x;
    unsigned int r = v.u + 0x7FFFu + ((v.u >> 16) & 1u);
    return (unsigned short)(r >> 16);
}
static __device__ __forceinline__ float bf2f(unsigned short v) {
    union { unsigned int u; float f; } w; w.u = ((unsigned int)v) << 16; return w.f;
}

// ---------------- prep: gather embeds, build masked-concat A (bf16) + query (bf16)
__global__ __launch_bounds__(256) void prep_kernel(
    const int* __restrict__ item_inputs,
    const int* __restrict__ label_inputs,
    const int* __restrict__ item_ids,
    const float* __restrict__ embeds,
    unsigned short* __restrict__ Abig,   // 16384 x 512 bf16
    unsigned short* __restrict__ qbf)    // 16384 x 256 bf16
{
    int t = threadIdx.x;
    int r = blockIdx.x * 4 + (t >> 6);
    int j = (t & 63) * 4;
    int item = item_inputs[r];
    int lab  = label_inputs[r];
    int qid  = item_ids[r];
    float4 e4 = *(const float4*)(embeds + (size_t)item * EMB + j);
    ushort4 on  = make_ushort4(f2bf(e4.x), f2bf(e4.y), f2bf(e4.z), f2bf(e4.w));
    ushort4 off = make_ushort4(0, 0, 0, 0);
    *(ushort4*)(Abig + (size_t)r * 512 + j)       = lab ? on : off;
    *(ushort4*)(Abig + (size_t)r * 512 + 256 + j) = lab ? off : on;
    float4 q4 = *(const float4*)(embeds + (size_t)qid * EMB + j);
    *(ushort4*)(qbf + (size_t)r * 256 + j) =
        make_ushort4(f2bf(q4.x), f2bf(q4.y), f2bf(q4.z), f2bf(q4.w));
}

// ---------------- merged weight prep + logits init + den-workspace zeroing
__global__ __launch_bounds__(256) void wcombo_kernel(
    const float* __restrict__ W_in,
    const float* __restrict__ Wq,
    const float* __restrict__ Wk,
    const float* __restrict__ Wv,
    const float* __restrict__ Wout,
    const float* __restrict__ bv,
    const float* __restrict__ bout,
    unsigned short* __restrict__ WTin,   // 256 x 512
    unsigned short* __restrict__ WTq,    // 256 x 256
    unsigned short* __restrict__ WTk,    // 256 x 256
    float* __restrict__ Wvw,             // 256 x 8
    float* __restrict__ bvw,             // 8
    float* __restrict__ logits,          // init to bout
    float* __restrict__ denbuf)          // 163840 floats -> zero
{
    int idx = blockIdx.x * 256 + threadIdx.x;
    if (idx < 131072) {                       // WTin[n][k] = W_in[k][n], K=512
        int n = idx >> 9, k = idx & 511;
        WTin[idx] = f2bf(W_in[(size_t)k * 256 + n]);
    } else if (idx < 196608) {                // WTq, K=256
        int i = idx - 131072;
        int n = i >> 8, k = i & 255;
        WTq[i] = f2bf(Wq[(size_t)k * 256 + n]);
    } else if (idx < 262144) {                // WTk, K=256
        int i = idx - 196608;
        int n = i >> 8, k = i & 255;
        WTk[i] = f2bf(Wk[(size_t)k * 256 + n]);
    } else if (idx < 264192) {                // Wvw[c][h] = sum_d Wv[c][32h+d]*Wout[32h+d]
        int i = idx - 262144;
        int c = i >> 3, h = i & 7;
        float s = 0.f;
        #pragma unroll
        for (int d = 0; d < 32; d++) s += Wv[(size_t)c * 256 + h * 32 + d] * Wout[h * 32 + d];
        Wvw[i] = s;
    } else if (idx < 264200) {                // bvw[h]
        int h = idx - 264192;
        float s = 0.f;
        #pragma unroll
        for (int d = 0; d < 32; d++) s += bv[h * 32 + d] * Wout[h * 32 + d];
        bvw[h] = s;
    } else if (idx < 280584) {                // logits init = bout
        logits[idx - 264200] = bout[0];
    } else if (idx < 444424) {                // zero denp/dent/denr (contiguous)
        denbuf[idx - 280584] = 0.f;
    }
}

// ---------------- MFMA GEMM body: C(M x 256) = A(M x KDIM) * BT^T + bias
template<int KDIM, int RELU, int OUTBF>
static __device__ __forceinline__ void gemm_body(
    const unsigned short* __restrict__ A,
    const unsigned short* __restrict__ BT,
    const float* __restrict__ bias,
    void* __restrict__ Cout, float scale)
{
    __shared__ unsigned short As[64][40];
    __shared__ unsigned short Bs[128][40];
    const int t = threadIdx.x;
    const int row0 = blockIdx.x * 64;
    const int col0 = blockIdx.y * 128;
    const int wid = t >> 6, lane = t & 63;
    const int wm = wid & 1, wn = wid >> 1;
    const int lg = lane >> 4, l15 = lane & 15;

    f32x4 acc[2][4];
    #pragma unroll
    for (int i = 0; i < 2; i++)
        #pragma unroll
        for (int j = 0; j < 4; j++) acc[i][j] = (f32x4){0.f, 0.f, 0.f, 0.f};

    const int arow = t >> 2, achk = t & 3;
    const int brow = t >> 1, bhalf = t & 1;

    for (int k0 = 0; k0 < KDIM; k0 += 32) {
        __syncthreads();
        *(uint4*)(&As[arow][achk * 8]) =
            *(const uint4*)(A + (size_t)(row0 + arow) * KDIM + k0 + achk * 8);
        const unsigned short* bsrc = BT + (size_t)(col0 + brow) * KDIM + k0 + bhalf * 16;
        *(uint4*)(&Bs[brow][bhalf * 16])     = *(const uint4*)(bsrc);
        *(uint4*)(&Bs[brow][bhalf * 16 + 8]) = *(const uint4*)(bsrc + 8);
        __syncthreads();
        bf16x8 af[2], bfr[4];
        #pragma unroll
        for (int fm = 0; fm < 2; fm++)
            af[fm] = *(const bf16x8*)(&As[wm * 32 + fm * 16 + l15][lg * 8]);
        #pragma unroll
        for (int fn = 0; fn < 4; fn++)
            bfr[fn] = *(const bf16x8*)(&Bs[wn * 64 + fn * 16 + l15][lg * 8]);
        #pragma unroll
        for (int fm = 0; fm < 2; fm++)
            #pragma unroll
            for (int fn = 0; fn < 4; fn++)
                acc[fm][fn] = __builtin_amdgcn_mfma_f32_16x16x32_bf16(
                    af[fm], bfr[fn], acc[fm][fn], 0, 0, 0);
    }
    #pragma unroll
    for (int fm = 0; fm < 2; fm++)
        #pragma unroll
        for (int fn = 0; fn < 4; fn++) {
            int col = col0 + wn * 64 + fn * 16 + l15;
            float bvv = bias[col];
            #pragma unroll
            for (int r = 0; r < 4; r++) {
                int row = row0 + wm * 32 + fm * 16 + lg * 4 + r;
                float v = acc[fm][fn][r] + bvv;
                if (RELU) v = fmaxf(v, 0.f);
                v *= scale;
                if (OUTBF) ((unsigned short*)Cout)[(size_t)row * 256 + col] = f2bf(v);
                else       ((float*)Cout)[(size_t)row * 256 + col] = v;
            }
        }
}

__global__ __launch_bounds__(256, 2) void gemm512_kernel(
    const unsigned short* __restrict__ A,
    const unsigned short* __restrict__ BT,
    const float* __restrict__ bias,
    unsigned short* __restrict__ Cout)
{
    gemm_body<512, 1, 1>(A, BT, bias, (void*)Cout, 1.0f);
}

// ---------------- Vw body: Vw[row][h] = X[row]·Wvw[:,h] + bvw[h]
static __device__ __forceinline__ void vw_body(
    const unsigned short* __restrict__ Xbf,
    const float* __restrict__ Wvw,
    const float* __restrict__ bvw,
    float* __restrict__ Vw)
{
    __shared__ float sW[2048];
    __shared__ float sb[8];
    int t = threadIdx.x;
    #pragma unroll
    for (int i = 0; i < 8; i++) sW[i * 256 + t] = Wvw[i * 256 + t];
    if (t < 8) sb[t] = bvw[t];
    __syncthreads();
    int row = blockIdx.x * 256 + t;
    float acc[8];
    #pragma unroll
    for (int h = 0; h < 8; h++) acc[h] = sb[h];
    for (int d0 = 0; d0 < 32; d0++) {
        bf16x8 x = *(const bf16x8*)(Xbf + (size_t)row * 256 + d0 * 8);
        #pragma unroll
        for (int j = 0; j < 8; j++) {
            float xf = bf2f((unsigned short)x[j]);
            #pragma unroll
            for (int h = 0; h < 8; h++) acc[h] += xf * sW[(d0 * 8 + j) * 8 + h];
        }
    }
    *(float4*)(Vw + (size_t)row * 8)     = make_float4(acc[0], acc[1], acc[2], acc[3]);
    *(float4*)(Vw + (size_t)row * 8 + 4) = make_float4(acc[4], acc[5], acc[6], acc[7]);
}

// ---------------- fused Q-GEMM / K-GEMM / Vw in one launch (z selects)
__global__ __launch_bounds__(256, 2) void gemmQKV_kernel(
    const unsigned short* __restrict__ qbf,
    const unsigned short* __restrict__ WTq,
    const float* __restrict__ bq,
    unsigned short* __restrict__ Qbf,
    const unsigned short* __restrict__ Xbf,
    const unsigned short* __restrict__ WTk,
    const float* __restrict__ bk,
    unsigned short* __restrict__ Kbf,
    const float* __restrict__ Wvw,
    const float* __restrict__ bvw,
    float* __restrict__ Vw)
{
    if (blockIdx.z == 0) {
        gemm_body<256, 0, 1>(qbf, WTq, bq, (void*)Qbf, 0.17677669529663687f);
    } else if (blockIdx.z == 1) {
        gemm_body<256, 0, 1>(Xbf, WTk, bk, (void*)Kbf, 1.0f);
    } else {
        if (blockIdx.x >= 64 || blockIdx.y != 0) return;
        vw_body(Xbf, Wvw, bvw, Vw);
    }
}

// ---------------- attnD: denominator partials -> atomicAdd into den workspace
// grid 2048: id -> b (32) x qt (16) x kc (4); 256 threads = 4 waves
__global__ __launch_bounds__(256, 8) void attnD_kernel(
    const unsigned short* __restrict__ Qbf,
    const unsigned short* __restrict__ Kbf,
    const float* __restrict__ rel,
    const float* __restrict__ tsp,
    float* __restrict__ denp,    // [32][8][512]
    float* __restrict__ dent,    // [32][512]
    float* __restrict__ denr)    // [32][512]
{
    const int t = threadIdx.x;
    const int id = blockIdx.x;
    const int b  = id >> 6;
    const int qt = (id >> 2) & 15;
    const int kc = id & 3;
    const int q0 = qt * 32;
    const int w = t >> 6, lane = t & 63;
    const int l15 = lane & 15, lg = lane >> 4;

    // Q fragments for this wave's 2 heads
    bf16x8 aq[2][2];
    #pragma unroll
    for (int hh = 0; hh < 2; hh++)
        #pragma unroll
        for (int mf = 0; mf < 2; mf++)
            aq[hh][mf] = *(const bf16x8*)(Qbf +
                (size_t)(b * SEQ + q0 + mf * 16 + l15) * EMB + (2 * w + hh) * 32 + lg * 8);

    float dp[2][2][4] = {};
    #pragma unroll 1
    for (int i = 0; i < 4; i++) {
        const int kt = kc + 4 * i;
        if (kt > qt) break;
        const int k0 = kt * 32;
        #pragma unroll
        for (int hh = 0; hh < 2; hh++) {
            #pragma unroll
            for (int nf = 0; nf < 2; nf++) {
                bf16x8 bk = *(const bf16x8*)(Kbf +
                    (size_t)(b * SEQ + k0 + nf * 16 + l15) * EMB + (2 * w + hh) * 32 + lg * 8);
                const int kcol = k0 + nf * 16 + l15;
                #pragma unroll
                for (int mf = 0; mf < 2; mf++) {
                    f32x4 am = __builtin_amdgcn_mfma_f32_16x16x32_bf16(
                        aq[hh][mf], bk, (f32x4){0, 0, 0, 0}, 0, 0, 0);
                    #pragma unroll
                    for (int r = 0; r < 4; r++) {
                        const int qrow = q0 + mf * 16 + lg * 4 + r;
                        dp[hh][mf][r] += (kcol <= qrow) ? __expf(am[r]) : 0.f;
                    }
                }
            }
        }
    }

    // rel/ts: wave w handles tile kc + 4*w
    float dt[2][4] = {}, dr[2][4] = {};
    {
        const int kt2 = kc + 4 * w;
        if (kt2 <= qt) {
            const int k0 = kt2 * 32;
            #pragma unroll
            for (int mf = 0; mf < 2; mf++)
                #pragma unroll
                for (int r = 0; r < 4; r++) {
                    const int qrow = q0 + mf * 16 + lg * 4 + r;
                    const size_t base = ((size_t)(b * SEQ) + qrow) * SEQ + k0 + l15;
                    #pragma unroll
                    for (int nf = 0; nf < 2; nf++) {
                        const int kcol = k0 + nf * 16 + l15;
                        const bool va = kcol <= qrow;
                        float tv = tsp[base + nf * 16];
                        float rv = rel[base + nf * 16];
                        dt[mf][r] += va ? __expf(__expf(-fabsf(tv))) : 0.f;
                        dr[mf][r] += (va && rv != 0.f) ? __expf(rv) : 0.f;
                    }
                }
        }
    }

    // shfl-reduce over the 16 key lanes, then atomicAdd partials
    #pragma unroll
    for (int hh = 0; hh < 2; hh++)
        #pragma unroll
        for (int mf = 0; mf < 2; mf++)
            #pragma unroll
            for (int r = 0; r < 4; r++) {
                float v = dp[hh][mf][r];
                v += __shfl_xor(v, 1); v += __shfl_xor(v, 2);
                v += __shfl_xor(v, 4); v += __shfl_xor(v, 8);
                if (l15 == 0)
                    atomicAdd(&denp[((size_t)(b * NHEAD + 2 * w + hh)) * SEQ
                                    + q0 + mf * 16 + lg * 4 + r], v);
            }
    #pragma unroll
    for (int mf = 0; mf < 2; mf++)
        #pragma unroll
        for (int r = 0; r < 4; r++) {
            float v = dt[mf][r];
            v += __shfl_xor(v, 1); v += __shfl_xor(v, 2);
            v += __shfl_xor(v, 4); v += __shfl_xor(v, 8);
            float u = dr[mf][r];
            u += __shfl_xor(u, 1); u += __shfl_xor(u, 2);
            u += __shfl_xor(u, 4); u += __shfl_xor(u, 8);
            if (l15 == 0) {
                const int qrow = q0 + mf * 16 + lg * 4 + r;
                atomicAdd(&dent[b * SEQ + qrow], v);
                atomicAdd(&denr[b * SEQ + qrow], u);
            }
        }
}

// ---------------- attnW v2: per-tile x head-half blocks; 1 head/wave; 8 blocks/CU
// grid 16384: id -> b (32) x tile (256 = qt*16+kt) x half (2); 256 threads = 4 waves
__global__ __launch_bounds__(256, 8) void attnW_kernel(
    const unsigned short* __restrict__ Qbf,
    const unsigned short* __restrict__ Kbf,
    const float* __restrict__ Vw,
    const float* __restrict__ rel,
    const float* __restrict__ tsp,
    const float* __restrict__ denp,
    const float* __restrict__ dent,
    const float* __restrict__ denr,
    const float* __restrict__ pl1,
    const float* __restrict__ pl2,
    float* __restrict__ logits,
    float* __restrict__ attn)
{
    __shared__ float sT[4][32][33];
    __shared__ float slog[4][32];

    const int t = threadIdx.x;
    const int id = blockIdx.x;
    const int b = id >> 9;
    const int rest = id & 511;
    const int tile = rest >> 1;
    const int half = rest & 1;
    const int qt = tile >> 4, kt = tile & 15;
    const int q0 = qt * 32, k0 = kt * 32;
    const int hb = half * 4;

    // lane-coalesced write geometry: 8 consecutive lanes cover one 128B line
    const int row_g = t >> 3;     // 0..31 concurrent row slot
    const int col4  = (t & 7) * 4;

    if (kt > qt) {   // strictly-future tile: zero-fill this half's 4 heads
        const float4 z = make_float4(0.f, 0.f, 0.f, 0.f);
        #pragma unroll
        for (int step = 0; step < 4; step++) {
            const int ridx = step * 32 + row_g;       // 0..127
            const int h = hb + (ridx >> 5), qloc = ridx & 31;
            *(float4*)(attn + ((size_t)((b * NHEAD + h) * SEQ) + q0 + qloc) * SEQ
                       + k0 + col4) = z;
        }
        return;
    }

    const int w = t >> 6, lane = t & 63;
    const int l15 = lane & 15, lg = lane >> 4;
    const int h = hb + w;                 // one head per wave
    const float l1 = pl1[0], l2 = pl2[0];
    const float cp = (1.f - l1) * (1.f - l2);
    const float ct = (1.f - l1) * l2;
    const float cr = l1;

    // per-row stats + et/er in C-frag layout (head-independent)
    float invt[2][4], invr[2][4], et[2][4][2], er[2][4][2];
    #pragma unroll
    for (int mf = 0; mf < 2; mf++)
        #pragma unroll
        for (int r = 0; r < 4; r++) {
            const int qrow = q0 + mf * 16 + lg * 4 + r;
            float dt = dent[b * SEQ + qrow];
            float dr = denr[b * SEQ + qrow];
            invt[mf][r] = 1.f / dt;
            invr[mf][r] = dr > 0.f ? 1.f / dr : 0.f;
            const size_t base = ((size_t)(b * SEQ) + qrow) * SEQ + k0 + l15;
            #pragma unroll
            for (int nf = 0; nf < 2; nf++) {
                const int kcol = k0 + nf * 16 + l15;
                const bool va = kcol <= qrow;
                float tv = tsp[base + nf * 16];
                float rv = rel[base + nf * 16];
                et[mf][r][nf] = va ? __expf(__expf(-fabsf(tv))) : 0.f;
                er[mf][r][nf] = (va && rv != 0.f) ? __expf(rv) : 0.f;
            }
        }

    float plog[2][4] = {};
    {
        bf16x8 aq0 = *(const bf16x8*)(Qbf + (size_t)(b * SEQ + q0 + l15) * EMB + h * 32 + lg * 8);
        bf16x8 aq1 = *(const bf16x8*)(Qbf + (size_t)(b * SEQ + q0 + 16 + l15) * EMB + h * 32 + lg * 8);
        bf16x8 bk0 = *(const bf16x8*)(Kbf + (size_t)(b * SEQ + k0 + l15) * EMB + h * 32 + lg * 8);
        bf16x8 bk1 = *(const bf16x8*)(Kbf + (size_t)(b * SEQ + k0 + 16 + l15) * EMB + h * 32 + lg * 8);
        const float vw0 = Vw[(size_t)(b * SEQ + k0 + l15) * 8 + h];
        const float vw1 = Vw[(size_t)(b * SEQ + k0 + 16 + l15) * 8 + h];
        float invp[2][4];
        #pragma unroll
        for (int mf = 0; mf < 2; mf++)
            #pragma unroll
            for (int r = 0; r < 4; r++)
                invp[mf][r] = 1.f / denp[((size_t)(b * NHEAD + h)) * SEQ
                                         + q0 + mf * 16 + lg * 4 + r];
        f32x4 am[2][2];
        am[0][0] = __builtin_amdgcn_mfma_f32_16x16x32_bf16(aq0, bk0, (f32x4){0,0,0,0}, 0, 0, 0);
        am[0][1] = __builtin_amdgcn_mfma_f32_16x16x32_bf16(aq0, bk1, (f32x4){0,0,0,0}, 0, 0, 0);
        am[1][0] = __builtin_amdgcn_mfma_f32_16x16x32_bf16(aq1, bk0, (f32x4){0,0,0,0}, 0, 0, 0);
        am[1][1] = __builtin_amdgcn_mfma_f32_16x16x32_bf16(aq1, bk1, (f32x4){0,0,0,0}, 0, 0, 0);
        #pragma unroll
        for (int nf = 0; nf < 2; nf++) {
            const int kcol = k0 + nf * 16 + l15;
            const float vwv = nf ? vw1 : vw0;
            #pragma unroll
            for (int mf = 0; mf < 2; mf++)
                #pragma unroll
                for (int r = 0; r < 4; r++) {
                    const int qloc = mf * 16 + lg * 4 + r;
                    const int qrow = q0 + qloc;
                    float a = 0.f;
                    if (kcol <= qrow)
                        a = cp * __expf(am[mf][nf][r]) * invp[mf][r]
                          + ct * et[mf][r][nf] * invt[mf][r]
                          + cr * er[mf][r][nf] * invr[mf][r];
                    sT[w][qloc][nf * 16 + l15] = a;
                    plog[mf][r] = fmaf(a, vwv, plog[mf][r]);
                }
        }
    }
    __syncthreads();

    // lane-coalesced write-out: each step stores 32 full contiguous 128B lines
    #pragma unroll
    for (int step = 0; step < 4; step++) {
        const int ridx = step * 32 + row_g;           // 0..127
        const int hl = ridx >> 5, qloc = ridx & 31;
        const float* s = &sT[hl][qloc][col4];
        *(float4*)(attn + ((size_t)((b * NHEAD + hb + hl) * SEQ) + q0 + qloc) * SEQ
                   + k0 + col4) = make_float4(s[0], s[1], s[2], s[3]);
    }

    // logits partial: reduce over key lanes, cross-wave via LDS, one atomic per row
    #pragma unroll
    for (int mf = 0; mf < 2; mf++)
        #pragma unroll
        for (int r = 0; r < 4; r++) {
            float v = plog[mf][r];
            v += __shfl_xor(v, 1); v += __shfl_xor(v, 2);
            v += __shfl_xor(v, 4); v += __shfl_xor(v, 8);
            if (l15 == 0) slog[w][mf * 16 + lg * 4 + r] = v;
        }
    __syncthreads();
    if (t < 32)
        atomicAdd(&logits[b * SEQ + q0 + t],
                  slog[0][t] + slog[1][t] + slog[2][t] + slog[3][t]);
}

// ---------------- host launch ----------------
extern "C" void kernel_launch(void* const* d_in, const int* in_sizes, int n_in,
                              void* d_out, int out_size, void* d_ws, size_t ws_size,
                              hipStream_t stream)
{
    (void)in_sizes; (void)n_in; (void)out_size; (void)ws_size;
    const int*   item_inputs  = (const int*)d_in[0];
    const int*   label_inputs = (const int*)d_in[1];
    const int*   item_ids     = (const int*)d_in[2];
    const float* rel   = (const float*)d_in[3];
    const float* tsp   = (const float*)d_in[4];
    const float* emb   = (const float*)d_in[5];
    const float* W_in  = (const float*)d_in[6];
    const float* b_in  = (const float*)d_in[7];
    const float* Wq    = (const float*)d_in[8];
    const float* bq    = (const float*)d_in[9];
    const float* Wk    = (const float*)d_in[10];
    const float* bk    = (const float*)d_in[11];
    const float* Wv    = (const float*)d_in[12];
    const float* bv    = (const float*)d_in[13];
    const float* Wout  = (const float*)d_in[14];
    const float* bout  = (const float*)d_in[15];
    const float* l1    = (const float*)d_in[16];
    const float* l2    = (const float*)d_in[17];

    const size_t R = 16384;
    char* w = (char*)d_ws;
    unsigned short* Abig = (unsigned short*)w; w += R * 512 * 2;
    unsigned short* qbf  = (unsigned short*)w; w += R * 256 * 2;
    unsigned short* WTin = (unsigned short*)w; w += (size_t)256 * 512 * 2;
    unsigned short* WTq  = (unsigned short*)w; w += (size_t)256 * 256 * 2;
    unsigned short* WTk  = (unsigned short*)w; w += (size_t)256 * 256 * 2;
    unsigned short* Xbf  = (unsigned short*)w; w += R * 256 * 2;
    unsigned short* Qbf  = (unsigned short*)w; w += R * 256 * 2;
    unsigned short* Kbf  = (unsigned short*)w; w += R * 256 * 2;
    float* Wvw  = (float*)w; w += 2048 * 4;
    float* Vw   = (float*)w; w += R * 8 * 4;
    float* bvw  = (float*)w; w += 256;          // 8 floats + pad
    float* denp = (float*)w; w += (size_t)32 * NHEAD * SEQ * 4;   // 512 KB
    float* dent = (float*)w; w += (size_t)32 * SEQ * 4;           // 64 KB
    float* denr = (float*)w; w += (size_t)32 * SEQ * 4;           // 64 KB

    prep_kernel<<<dim3(4096), dim3(256), 0, stream>>>(
        item_inputs, label_inputs, item_ids, emb, Abig, qbf);
    // wcombo also zeroes denp/dent/denr (contiguous 163840 floats) and inits logits
    wcombo_kernel<<<dim3(1737), dim3(256), 0, stream>>>(
        W_in, Wq, Wk, Wv, Wout, bv, bout, WTin, WTq, WTk, Wvw, bvw,
        (float*)d_out, denp);

    gemm512_kernel<<<dim3(256, 2), dim3(256), 0, stream>>>(Abig, WTin, b_in, Xbf);
    gemmQKV_kernel<<<dim3(256, 2, 3), dim3(256), 0, stream>>>(
        qbf, WTq, bq, Qbf, Xbf, WTk, bk, Kbf, Wvw, bvw, Vw);

    float* logits = (float*)d_out;
    float* attnp  = (float*)d_out + 16384;
    attnD_kernel<<<dim3(2048), dim3(256), 0, stream>>>(
        Qbf, Kbf, rel, tsp, denp, dent, denr);
    attnW_kernel<<<dim3(16384), dim3(256), 0, stream>>>(
        Qbf, Kbf, Vw, rel, tsp, denp, dent, denr, l1, l2, logits, attnp);
}

// Round 8
// 195.393 us; speedup vs baseline: 2.0046x; 2.0046x over previous
//
#include <hip/hip_runtime.h>
#include <hip/hip_bf16.h>

#define SEQ 512
#define EMB 256
#define NHEAD 8
#define HD 32

using bf16x8 = __attribute__((ext_vector_type(8))) short;
using f32x4  = __attribute__((ext_vector_type(4))) float;

static __device__ __forceinline__ unsigned short f2bf(float x) {
    union { float f; unsigned int u; } v; v.f = x;
    unsigned int r = v.u + 0x7FFFu + ((v.u >> 16) & 1u);
    return (unsigned short)(r >> 16);
}
static __device__ __forceinline__ float bf2f(unsigned short v) {
    union { unsigned int u; float f; } w; w.u = ((unsigned int)v) << 16; return w.f;
}

// ---------------- prep: gather embeds, build masked-concat A (bf16) + query (bf16)
__global__ __launch_bounds__(256) void prep_kernel(
    const int* __restrict__ item_inputs,
    const int* __restrict__ label_inputs,
    const int* __restrict__ item_ids,
    const float* __restrict__ embeds,
    unsigned short* __restrict__ Abig,   // 16384 x 512 bf16
    unsigned short* __restrict__ qbf)    // 16384 x 256 bf16
{
    int t = threadIdx.x;
    int r = blockIdx.x * 4 + (t >> 6);
    int j = (t & 63) * 4;
    int item = item_inputs[r];
    int lab  = label_inputs[r];
    int qid  = item_ids[r];
    float4 e4 = *(const float4*)(embeds + (size_t)item * EMB + j);
    ushort4 on  = make_ushort4(f2bf(e4.x), f2bf(e4.y), f2bf(e4.z), f2bf(e4.w));
    ushort4 off = make_ushort4(0, 0, 0, 0);
    *(ushort4*)(Abig + (size_t)r * 512 + j)       = lab ? on : off;
    *(ushort4*)(Abig + (size_t)r * 512 + 256 + j) = lab ? off : on;
    float4 q4 = *(const float4*)(embeds + (size_t)qid * EMB + j);
    *(ushort4*)(qbf + (size_t)r * 256 + j) =
        make_ushort4(f2bf(q4.x), f2bf(q4.y), f2bf(q4.z), f2bf(q4.w));
}

// ---------------- merged weight prep + logits init + den-workspace zeroing
__global__ __launch_bounds__(256) void wcombo_kernel(
    const float* __restrict__ W_in,
    const float* __restrict__ Wq,
    const float* __restrict__ Wk,
    const float* __restrict__ Wv,
    const float* __restrict__ Wout,
    const float* __restrict__ bv,
    const float* __restrict__ bout,
    unsigned short* __restrict__ WTin,   // 256 x 512
    unsigned short* __restrict__ WTq,    // 256 x 256
    unsigned short* __restrict__ WTk,    // 256 x 256
    float* __restrict__ Wvw,             // 256 x 8
    float* __restrict__ bvw,             // 8
    float* __restrict__ logits,          // init to bout
    float* __restrict__ denbuf)          // 163840 floats -> zero
{
    int idx = blockIdx.x * 256 + threadIdx.x;
    if (idx < 131072) {                       // WTin[n][k] = W_in[k][n], K=512
        int n = idx >> 9, k = idx & 511;
        WTin[idx] = f2bf(W_in[(size_t)k * 256 + n]);
    } else if (idx < 196608) {                // WTq, K=256
        int i = idx - 131072;
        int n = i >> 8, k = i & 255;
        WTq[i] = f2bf(Wq[(size_t)k * 256 + n]);
    } else if (idx < 262144) {                // WTk, K=256
        int i = idx - 196608;
        int n = i >> 8, k = i & 255;
        WTk[i] = f2bf(Wk[(size_t)k * 256 + n]);
    } else if (idx < 264192) {                // Wvw[c][h] = sum_d Wv[c][32h+d]*Wout[32h+d]
        int i = idx - 262144;
        int c = i >> 3, h = i & 7;
        float s = 0.f;
        #pragma unroll
        for (int d = 0; d < 32; d++) s += Wv[(size_t)c * 256 + h * 32 + d] * Wout[h * 32 + d];
        Wvw[i] = s;
    } else if (idx < 264200) {                // bvw[h]
        int h = idx - 264192;
        float s = 0.f;
        #pragma unroll
        for (int d = 0; d < 32; d++) s += bv[h * 32 + d] * Wout[h * 32 + d];
        bvw[h] = s;
    } else if (idx < 280584) {                // logits init = bout
        logits[idx - 264200] = bout[0];
    } else if (idx < 444424) {                // zero denp/dent/denr (contiguous)
        denbuf[idx - 280584] = 0.f;
    }
}

// ---------------- MFMA GEMM body: C(M x 256) = A(M x KDIM) * BT^T + bias
template<int KDIM, int RELU, int OUTBF>
static __device__ __forceinline__ void gemm_body(
    const unsigned short* __restrict__ A,
    const unsigned short* __restrict__ BT,
    const float* __restrict__ bias,
    void* __restrict__ Cout, float scale)
{
    __shared__ unsigned short As[64][40];
    __shared__ unsigned short Bs[128][40];
    const int t = threadIdx.x;
    const int row0 = blockIdx.x * 64;
    const int col0 = blockIdx.y * 128;
    const int wid = t >> 6, lane = t & 63;
    const int wm = wid & 1, wn = wid >> 1;
    const int lg = lane >> 4, l15 = lane & 15;

    f32x4 acc[2][4];
    #pragma unroll
    for (int i = 0; i < 2; i++)
        #pragma unroll
        for (int j = 0; j < 4; j++) acc[i][j] = (f32x4){0.f, 0.f, 0.f, 0.f};

    const int arow = t >> 2, achk = t & 3;
    const int brow = t >> 1, bhalf = t & 1;

    for (int k0 = 0; k0 < KDIM; k0 += 32) {
        __syncthreads();
        *(uint4*)(&As[arow][achk * 8]) =
            *(const uint4*)(A + (size_t)(row0 + arow) * KDIM + k0 + achk * 8);
        const unsigned short* bsrc = BT + (size_t)(col0 + brow) * KDIM + k0 + bhalf * 16;
        *(uint4*)(&Bs[brow][bhalf * 16])     = *(const uint4*)(bsrc);
        *(uint4*)(&Bs[brow][bhalf * 16 + 8]) = *(const uint4*)(bsrc + 8);
        __syncthreads();
        bf16x8 af[2], bfr[4];
        #pragma unroll
        for (int fm = 0; fm < 2; fm++)
            af[fm] = *(const bf16x8*)(&As[wm * 32 + fm * 16 + l15][lg * 8]);
        #pragma unroll
        for (int fn = 0; fn < 4; fn++)
            bfr[fn] = *(const bf16x8*)(&Bs[wn * 64 + fn * 16 + l15][lg * 8]);
        #pragma unroll
        for (int fm = 0; fm < 2; fm++)
            #pragma unroll
            for (int fn = 0; fn < 4; fn++)
                acc[fm][fn] = __builtin_amdgcn_mfma_f32_16x16x32_bf16(
                    af[fm], bfr[fn], acc[fm][fn], 0, 0, 0);
    }
    #pragma unroll
    for (int fm = 0; fm < 2; fm++)
        #pragma unroll
        for (int fn = 0; fn < 4; fn++) {
            int col = col0 + wn * 64 + fn * 16 + l15;
            float bvv = bias[col];
            #pragma unroll
            for (int r = 0; r < 4; r++) {
                int row = row0 + wm * 32 + fm * 16 + lg * 4 + r;
                float v = acc[fm][fn][r] + bvv;
                if (RELU) v = fmaxf(v, 0.f);
                v *= scale;
                if (OUTBF) ((unsigned short*)Cout)[(size_t)row * 256 + col] = f2bf(v);
                else       ((float*)Cout)[(size_t)row * 256 + col] = v;
            }
        }
}

__global__ __launch_bounds__(256, 2) void gemm512_kernel(
    const unsigned short* __restrict__ A,
    const unsigned short* __restrict__ BT,
    const float* __restrict__ bias,
    unsigned short* __restrict__ Cout)
{
    gemm_body<512, 1, 1>(A, BT, bias, (void*)Cout, 1.0f);
}

// ---------------- Vw body: Vw[row][h] = X[row]·Wvw[:,h] + bvw[h]
static __device__ __forceinline__ void vw_body(
    const unsigned short* __restrict__ Xbf,
    const float* __restrict__ Wvw,
    const float* __restrict__ bvw,
    float* __restrict__ Vw)
{
    __shared__ float sW[2048];
    __shared__ float sb[8];
    int t = threadIdx.x;
    #pragma unroll
    for (int i = 0; i < 8; i++) sW[i * 256 + t] = Wvw[i * 256 + t];
    if (t < 8) sb[t] = bvw[t];
    __syncthreads();
    int row = blockIdx.x * 256 + t;
    float acc[8];
    #pragma unroll
    for (int h = 0; h < 8; h++) acc[h] = sb[h];
    for (int d0 = 0; d0 < 32; d0++) {
        bf16x8 x = *(const bf16x8*)(Xbf + (size_t)row * 256 + d0 * 8);
        #pragma unroll
        for (int j = 0; j < 8; j++) {
            float xf = bf2f((unsigned short)x[j]);
            #pragma unroll
            for (int h = 0; h < 8; h++) acc[h] += xf * sW[(d0 * 8 + j) * 8 + h];
        }
    }
    *(float4*)(Vw + (size_t)row * 8)     = make_float4(acc[0], acc[1], acc[2], acc[3]);
    *(float4*)(Vw + (size_t)row * 8 + 4) = make_float4(acc[4], acc[5], acc[6], acc[7]);
}

// ---------------- fused Q-GEMM / K-GEMM / Vw in one launch (z selects)
__global__ __launch_bounds__(256, 2) void gemmQKV_kernel(
    const unsigned short* __restrict__ qbf,
    const unsigned short* __restrict__ WTq,
    const float* __restrict__ bq,
    unsigned short* __restrict__ Qbf,
    const unsigned short* __restrict__ Xbf,
    const unsigned short* __restrict__ WTk,
    const float* __restrict__ bk,
    unsigned short* __restrict__ Kbf,
    const float* __restrict__ Wvw,
    const float* __restrict__ bvw,
    float* __restrict__ Vw)
{
    if (blockIdx.z == 0) {
        gemm_body<256, 0, 1>(qbf, WTq, bq, (void*)Qbf, 0.17677669529663687f);
    } else if (blockIdx.z == 1) {
        gemm_body<256, 0, 1>(Xbf, WTk, bk, (void*)Kbf, 1.0f);
    } else {
        if (blockIdx.x >= 64 || blockIdx.y != 0) return;
        vw_body(Xbf, Wvw, bvw, Vw);
    }
}

// ---------------- attnD: denominator partials -> atomicAdd into den workspace
// grid 2048: id -> b (32) x qt (16) x kc (4); 256 threads = 4 waves
__global__ __launch_bounds__(256, 8) void attnD_kernel(
    const unsigned short* __restrict__ Qbf,
    const unsigned short* __restrict__ Kbf,
    const float* __restrict__ rel,
    const float* __restrict__ tsp,
    float* __restrict__ denp,    // [32][8][512]
    float* __restrict__ dent,    // [32][512]
    float* __restrict__ denr)    // [32][512]
{
    const int t = threadIdx.x;
    const int id = blockIdx.x;
    const int b  = id >> 6;
    const int qt = (id >> 2) & 15;
    const int kc = id & 3;
    const int q0 = qt * 32;
    const int w = t >> 6, lane = t & 63;
    const int l15 = lane & 15, lg = lane >> 4;

    // Q fragments for this wave's 2 heads
    bf16x8 aq[2][2];
    #pragma unroll
    for (int hh = 0; hh < 2; hh++)
        #pragma unroll
        for (int mf = 0; mf < 2; mf++)
            aq[hh][mf] = *(const bf16x8*)(Qbf +
                (size_t)(b * SEQ + q0 + mf * 16 + l15) * EMB + (2 * w + hh) * 32 + lg * 8);

    float dp[2][2][4] = {};
    #pragma unroll 1
    for (int i = 0; i < 4; i++) {
        const int kt = kc + 4 * i;
        if (kt > qt) break;
        const int k0 = kt * 32;
        #pragma unroll
        for (int hh = 0; hh < 2; hh++) {
            #pragma unroll
            for (int nf = 0; nf < 2; nf++) {
                bf16x8 bk = *(const bf16x8*)(Kbf +
                    (size_t)(b * SEQ + k0 + nf * 16 + l15) * EMB + (2 * w + hh) * 32 + lg * 8);
                const int kcol = k0 + nf * 16 + l15;
                #pragma unroll
                for (int mf = 0; mf < 2; mf++) {
                    f32x4 am = __builtin_amdgcn_mfma_f32_16x16x32_bf16(
                        aq[hh][mf], bk, (f32x4){0, 0, 0, 0}, 0, 0, 0);
                    #pragma unroll
                    for (int r = 0; r < 4; r++) {
                        const int qrow = q0 + mf * 16 + lg * 4 + r;
                        dp[hh][mf][r] += (kcol <= qrow) ? __expf(am[r]) : 0.f;
                    }
                }
            }
        }
    }

    // rel/ts: wave w handles tile kc + 4*w
    float dt[2][4] = {}, dr[2][4] = {};
    {
        const int kt2 = kc + 4 * w;
        if (kt2 <= qt) {
            const int k0 = kt2 * 32;
            #pragma unroll
            for (int mf = 0; mf < 2; mf++)
                #pragma unroll
                for (int r = 0; r < 4; r++) {
                    const int qrow = q0 + mf * 16 + lg * 4 + r;
                    const size_t base = ((size_t)(b * SEQ) + qrow) * SEQ + k0 + l15;
                    #pragma unroll
                    for (int nf = 0; nf < 2; nf++) {
                        const int kcol = k0 + nf * 16 + l15;
                        const bool va = kcol <= qrow;
                        float tv = tsp[base + nf * 16];
                        float rv = rel[base + nf * 16];
                        dt[mf][r] += va ? __expf(__expf(-fabsf(tv))) : 0.f;
                        dr[mf][r] += (va && rv != 0.f) ? __expf(rv) : 0.f;
                    }
                }
        }
    }

    // shfl-reduce over the 16 key lanes, then atomicAdd partials
    #pragma unroll
    for (int hh = 0; hh < 2; hh++)
        #pragma unroll
        for (int mf = 0; mf < 2; mf++)
            #pragma unroll
            for (int r = 0; r < 4; r++) {
                float v = dp[hh][mf][r];
                v += __shfl_xor(v, 1); v += __shfl_xor(v, 2);
                v += __shfl_xor(v, 4); v += __shfl_xor(v, 8);
                if (l15 == 0)
                    atomicAdd(&denp[((size_t)(b * NHEAD + 2 * w + hh)) * SEQ
                                    + q0 + mf * 16 + lg * 4 + r], v);
            }
    #pragma unroll
    for (int mf = 0; mf < 2; mf++)
        #pragma unroll
        for (int r = 0; r < 4; r++) {
            float v = dt[mf][r];
            v += __shfl_xor(v, 1); v += __shfl_xor(v, 2);
            v += __shfl_xor(v, 4); v += __shfl_xor(v, 8);
            float u = dr[mf][r];
            u += __shfl_xor(u, 1); u += __shfl_xor(u, 2);
            u += __shfl_xor(u, 4); u += __shfl_xor(u, 8);
            if (l15 == 0) {
                const int qrow = q0 + mf * 16 + lg * 4 + r;
                atomicAdd(&dent[b * SEQ + qrow], v);
                atomicAdd(&denr[b * SEQ + qrow], u);
            }
        }
}

// ---------------- attnB: head-independent blend term, uniform triangular grid
// blend[b][q][k] = ct*et[q,k]/dent[q] + cr*er[q,k]/denr[q]  (masked)
// grid 4352: id -> b (32) x tri-tile (136); 256 threads, 1 float4/thread
__global__ __launch_bounds__(256, 8) void attnB_kernel(
    const float* __restrict__ rel,
    const float* __restrict__ tsp,
    const float* __restrict__ dent,
    const float* __restrict__ denr,
    const float* __restrict__ pl1,
    const float* __restrict__ pl2,
    float* __restrict__ blend)
{
    const int t = threadIdx.x;
    const int id = blockIdx.x;
    const int b = id & 31;
    const int i = id >> 5;            // 0..135 triangular index
    int qt = (int)((__fsqrt_rn(8.f * i + 1.f) - 1.f) * 0.5f);
    if ((qt + 1) * (qt + 2) / 2 <= i) qt++;
    if (qt * (qt + 1) / 2 > i) qt--;
    const int kt = i - qt * (qt + 1) / 2;
    const int q0 = qt * 32, k0 = kt * 32;

    const float l1 = pl1[0], l2 = pl2[0];
    const float ct = (1.f - l1) * l2;
    const float cr = l1;

    const int rr = t >> 3, cc4 = (t & 7) * 4;
    const int qrow = q0 + rr;
    const float invt = ct / dent[b * SEQ + qrow];
    const float drv = denr[b * SEQ + qrow];
    const float invr = drv > 0.f ? cr / drv : 0.f;

    const size_t gi = ((size_t)(b * SEQ) + qrow) * SEQ + k0 + cc4;
    float4 tv4 = *(const float4*)(tsp + gi);
    float4 rv4 = *(const float4*)(rel + gi);
    const float* tvp = &tv4.x;
    const float* rvp = &rv4.x;
    float4 o;
    float* op = &o.x;
    #pragma unroll
    for (int j = 0; j < 4; j++) {
        const bool va = (k0 + cc4 + j) <= qrow;
        float e_t = va ? __expf(__expf(-fabsf(tvp[j]))) * invt : 0.f;
        float e_r = (va && rvp[j] != 0.f) ? __expf(rvp[j]) * invr : 0.f;
        op[j] = e_t + e_r;
    }
    *(float4*)(blend + gi) = o;
}

// ---------------- attnW v3: block = (b, head, 16-row strip, ALL k) -> contiguous writes
// grid 8192: id -> b (32) x h (8) x qt16 (32, heavy-first); 256 threads = 4 waves
__global__ __launch_bounds__(256, 8) void attnW_kernel(
    const unsigned short* __restrict__ Qbf,
    const unsigned short* __restrict__ Kbf,
    const float* __restrict__ Vw,
    const float* __restrict__ denp,
    const float* __restrict__ blend,
    const float* __restrict__ pl1,
    const float* __restrict__ pl2,
    float* __restrict__ logits,
    float* __restrict__ attn)
{
    __shared__ float sT[16][260];
    __shared__ float slog[4][16];

    const int t = threadIdx.x;
    const int id = blockIdx.x;
    const int b = id & 31;
    const int h = (id >> 5) & 7;
    const int qt16 = 31 - (id >> 8);      // heavy strips dispatched first
    const int q0 = qt16 * 16;
    const int qmax = q0 + 15;

    const int w = t >> 6, lane = t & 63;
    const int l15 = lane & 15, lg = lane >> 4;

    const float l1 = pl1[0], l2 = pl2[0];
    const float cp = (1.f - l1) * (1.f - l2);

    // Q fragment: rows q0+l15, dims h*32 + lg*8
    bf16x8 aq = *(const bf16x8*)(Qbf + (size_t)(b * SEQ + q0 + l15) * EMB + h * 32 + lg * 8);

    float invp[4];
    #pragma unroll
    for (int r = 0; r < 4; r++)
        invp[r] = 1.f / denp[((size_t)(b * NHEAD + h)) * SEQ + q0 + lg * 4 + r];

    float plog[4] = {0.f, 0.f, 0.f, 0.f};

    // prefetch / writeback geometry: row = t>>4, 4 float4s at 64-float steps
    const int wrow = t >> 4;
    const int wcol = (t & 15) * 4;
    float* arow_base = attn + ((size_t)((b * NHEAD + h) * SEQ) + q0 + wrow) * SEQ;
    const float* brow_base = blend + ((size_t)(b * SEQ) + q0 + wrow) * SEQ;

    for (int pass = 0; pass < 2; pass++) {
        const int c0 = pass * 256;
        // prefetch blend tile (coalesced 256B segments); invalid region garbage, overwritten
        #pragma unroll
        for (int s = 0; s < 4; s++) {
            const int cf = wcol + s * 64;
            *(float4*)(&sT[wrow][cf]) = *(const float4*)(brow_base + c0 + cf);
        }
        __syncthreads();
        // compute: wave w handles kt = w and w+4 of the 8 kt32 tiles in this pass
        #pragma unroll
        for (int ki = 0; ki < 2; ki++) {
            const int kt = w + ki * 4;
            const int k0 = c0 + kt * 32;
            if (k0 <= qmax) {
                #pragma unroll
                for (int nf = 0; nf < 2; nf++) {
                    const int kcol = k0 + nf * 16 + l15;
                    const int lcol = kt * 32 + nf * 16 + l15;
                    bf16x8 bk = *(const bf16x8*)(Kbf +
                        (size_t)(b * SEQ + kcol) * EMB + h * 32 + lg * 8);
                    const float vwv = Vw[(size_t)(b * SEQ + kcol) * 8 + h];
                    f32x4 am = __builtin_amdgcn_mfma_f32_16x16x32_bf16(
                        aq, bk, (f32x4){0.f, 0.f, 0.f, 0.f}, 0, 0, 0);
                    #pragma unroll
                    for (int r = 0; r < 4; r++) {
                        const int qloc = lg * 4 + r;
                        float a = 0.f;
                        if (kcol <= q0 + qloc)
                            a = fmaf(cp * __expf(am[r]), invp[r], sT[qloc][lcol]);
                        sT[qloc][lcol] = a;
                        plog[r] = fmaf(a, vwv, plog[r]);
                    }
                }
            } else {
                #pragma unroll
                for (int nf = 0; nf < 2; nf++) {
                    const int lcol = kt * 32 + nf * 16 + l15;
                    #pragma unroll
                    for (int r = 0; r < 4; r++)
                        sT[lg * 4 + r][lcol] = 0.f;
                }
            }
        }
        __syncthreads();
        // writeback: 16 full rows, 256B-contiguous segments per 16-lane group
        #pragma unroll
        for (int s = 0; s < 4; s++) {
            const int cf = wcol + s * 64;
            const float* sp = &sT[wrow][cf];
            *(float4*)(arow_base + c0 + cf) = make_float4(sp[0], sp[1], sp[2], sp[3]);
        }
        __syncthreads();
    }

    // logits partials: reduce over 16 key lanes, cross-wave via LDS, 1 atomic/row
    #pragma unroll
    for (int r = 0; r < 4; r++) {
        float v = plog[r];
        v += __shfl_xor(v, 1); v += __shfl_xor(v, 2);
        v += __shfl_xor(v, 4); v += __shfl_xor(v, 8);
        if (l15 == 0) slog[w][lg * 4 + r] = v;
    }
    __syncthreads();
    if (t < 16)
        atomicAdd(&logits[b * SEQ + q0 + t],
                  slog[0][t] + slog[1][t] + slog[2][t] + slog[3][t]);
}

// ---------------- host launch ----------------
extern "C" void kernel_launch(void* const* d_in, const int* in_sizes, int n_in,
                              void* d_out, int out_size, void* d_ws, size_t ws_size,
                              hipStream_t stream)
{
    (void)in_sizes; (void)n_in; (void)out_size; (void)ws_size;
    const int*   item_inputs  = (const int*)d_in[0];
    const int*   label_inputs = (const int*)d_in[1];
    const int*   item_ids     = (const int*)d_in[2];
    const float* rel   = (const float*)d_in[3];
    const float* tsp   = (const float*)d_in[4];
    const float* emb   = (const float*)d_in[5];
    const float* W_in  = (const float*)d_in[6];
    const float* b_in  = (const float*)d_in[7];
    const float* Wq    = (const float*)d_in[8];
    const float* bq    = (const float*)d_in[9];
    const float* Wk    = (const float*)d_in[10];
    const float* bk    = (const float*)d_in[11];
    const float* Wv    = (const float*)d_in[12];
    const float* bv    = (const float*)d_in[13];
    const float* Wout  = (const float*)d_in[14];
    const float* bout  = (const float*)d_in[15];
    const float* l1    = (const float*)d_in[16];
    const float* l2    = (const float*)d_in[17];

    const size_t R = 16384;
    char* w = (char*)d_ws;
    unsigned short* Abig = (unsigned short*)w; w += R * 512 * 2;
    unsigned short* qbf  = (unsigned short*)w; w += R * 256 * 2;
    unsigned short* WTin = (unsigned short*)w; w += (size_t)256 * 512 * 2;
    unsigned short* WTq  = (unsigned short*)w; w += (size_t)256 * 256 * 2;
    unsigned short* WTk  = (unsigned short*)w; w += (size_t)256 * 256 * 2;
    unsigned short* Xbf  = (unsigned short*)w; w += R * 256 * 2;
    unsigned short* Qbf  = (unsigned short*)w; w += R * 256 * 2;
    unsigned short* Kbf  = (unsigned short*)w; w += R * 256 * 2;
    float* Wvw  = (float*)w; w += 2048 * 4;
    float* Vw   = (float*)w; w += R * 8 * 4;
    float* bvw  = (float*)w; w += 256;          // 8 floats + pad
    float* denp = (float*)w; w += (size_t)32 * NHEAD * SEQ * 4;   // 512 KB
    float* dent = (float*)w; w += (size_t)32 * SEQ * 4;           // 64 KB
    float* denr = (float*)w; w += (size_t)32 * SEQ * 4;           // 64 KB
    float* blend = (float*)w; w += (size_t)32 * SEQ * SEQ * 4;    // 33.5 MB

    prep_kernel<<<dim3(4096), dim3(256), 0, stream>>>(
        item_inputs, label_inputs, item_ids, emb, Abig, qbf);
    // wcombo also zeroes denp/dent/denr (contiguous 163840 floats) and inits logits
    wcombo_kernel<<<dim3(1737), dim3(256), 0, stream>>>(
        W_in, Wq, Wk, Wv, Wout, bv, bout, WTin, WTq, WTk, Wvw, bvw,
        (float*)d_out, denp);

    gemm512_kernel<<<dim3(256, 2), dim3(256), 0, stream>>>(Abig, WTin, b_in, Xbf);
    gemmQKV_kernel<<<dim3(256, 2, 3), dim3(256), 0, stream>>>(
        qbf, WTq, bq, Qbf, Xbf, WTk, bk, Kbf, Wvw, bvw, Vw);

    float* logits = (float*)d_out;
    float* attnp  = (float*)d_out + 16384;
    attnD_kernel<<<dim3(2048), dim3(256), 0, stream>>>(
        Qbf, Kbf, rel, tsp, denp, dent, denr);
    attnB_kernel<<<dim3(4352), dim3(256), 0, stream>>>(
        rel, tsp, dent, denr, l1, l2, blend);
    attnW_kernel<<<dim3(8192), dim3(256), 0, stream>>>(
        Qbf, Kbf, Vw, denp, blend, l1, l2, logits, attnp);
}

// Round 10
// 181.760 us; speedup vs baseline: 2.1550x; 1.0750x over previous
//
#include <hip/hip_runtime.h>
#include <hip/hip_bf16.h>

#define SEQ 512
#define EMB 256
#define NHEAD 8
#define HD 32

using bf16x8 = __attribute__((ext_vector_type(8))) short;
using f32x4  = __attribute__((ext_vector_type(4))) float;

static __device__ __forceinline__ unsigned short f2bf(float x) {
    union { float f; unsigned int u; } v; v.f = x;
    unsigned int r = v.u + 0x7FFFu + ((v.u >> 16) & 1u);
    return (unsigned short)(r >> 16);
}
static __device__ __forceinline__ float bf2f(unsigned short v) {
    union { unsigned int u; float f; } w; w.u = ((unsigned int)v) << 16; return w.f;
}

// ---------------- prep: gather embeds, build masked-concat A (bf16) + query (bf16)
__global__ __launch_bounds__(256) void prep_kernel(
    const int* __restrict__ item_inputs,
    const int* __restrict__ label_inputs,
    const int* __restrict__ item_ids,
    const float* __restrict__ embeds,
    unsigned short* __restrict__ Abig,   // 16384 x 512 bf16
    unsigned short* __restrict__ qbf)    // 16384 x 256 bf16
{
    int t = threadIdx.x;
    int r = blockIdx.x * 4 + (t >> 6);
    int j = (t & 63) * 4;
    int item = item_inputs[r];
    int lab  = label_inputs[r];
    int qid  = item_ids[r];
    float4 e4 = *(const float4*)(embeds + (size_t)item * EMB + j);
    ushort4 on  = make_ushort4(f2bf(e4.x), f2bf(e4.y), f2bf(e4.z), f2bf(e4.w));
    ushort4 off = make_ushort4(0, 0, 0, 0);
    *(ushort4*)(Abig + (size_t)r * 512 + j)       = lab ? on : off;
    *(ushort4*)(Abig + (size_t)r * 512 + 256 + j) = lab ? off : on;
    float4 q4 = *(const float4*)(embeds + (size_t)qid * EMB + j);
    *(ushort4*)(qbf + (size_t)r * 256 + j) =
        make_ushort4(f2bf(q4.x), f2bf(q4.y), f2bf(q4.z), f2bf(q4.w));
}

// ---------------- merged weight prep + logits init + den-workspace zeroing
__global__ __launch_bounds__(256) void wcombo_kernel(
    const float* __restrict__ W_in,
    const float* __restrict__ Wq,
    const float* __restrict__ Wk,
    const float* __restrict__ Wv,
    const float* __restrict__ Wout,
    const float* __restrict__ bv,
    const float* __restrict__ bout,
    unsigned short* __restrict__ WTin,   // 256 x 512
    unsigned short* __restrict__ WTq,    // 256 x 256
    unsigned short* __restrict__ WTk,    // 256 x 256
    float* __restrict__ Wvw,             // 256 x 8
    float* __restrict__ bvw,             // 8
    float* __restrict__ logits,          // init to bout
    float* __restrict__ denbuf)          // 163840 floats -> zero
{
    int idx = blockIdx.x * 256 + threadIdx.x;
    if (idx < 131072) {                       // WTin[n][k] = W_in[k][n], K=512
        int n = idx >> 9, k = idx & 511;
        WTin[idx] = f2bf(W_in[(size_t)k * 256 + n]);
    } else if (idx < 196608) {                // WTq, K=256
        int i = idx - 131072;
        int n = i >> 8, k = i & 255;
        WTq[i] = f2bf(Wq[(size_t)k * 256 + n]);
    } else if (idx < 262144) {                // WTk, K=256
        int i = idx - 196608;
        int n = i >> 8, k = i & 255;
        WTk[i] = f2bf(Wk[(size_t)k * 256 + n]);
    } else if (idx < 264192) {                // Wvw[c][h] = sum_d Wv[c][32h+d]*Wout[32h+d]
        int i = idx - 262144;
        int c = i >> 3, h = i & 7;
        float s = 0.f;
        #pragma unroll
        for (int d = 0; d < 32; d++) s += Wv[(size_t)c * 256 + h * 32 + d] * Wout[h * 32 + d];
        Wvw[i] = s;
    } else if (idx < 264200) {                // bvw[h]
        int h = idx - 264192;
        float s = 0.f;
        #pragma unroll
        for (int d = 0; d < 32; d++) s += bv[h * 32 + d] * Wout[h * 32 + d];
        bvw[h] = s;
    } else if (idx < 280584) {                // logits init = bout
        logits[idx - 264200] = bout[0];
    } else if (idx < 444424) {                // zero denp/dent/denr (contiguous)
        denbuf[idx - 280584] = 0.f;
    }
}

// ---------------- MFMA GEMM body: C(M x 256) = A(M x KDIM) * BT^T + bias
template<int KDIM, int RELU, int OUTBF>
static __device__ __forceinline__ void gemm_body(
    const unsigned short* __restrict__ A,
    const unsigned short* __restrict__ BT,
    const float* __restrict__ bias,
    void* __restrict__ Cout, float scale)
{
    __shared__ unsigned short As[64][40];
    __shared__ unsigned short Bs[128][40];
    const int t = threadIdx.x;
    const int row0 = blockIdx.x * 64;
    const int col0 = blockIdx.y * 128;
    const int wid = t >> 6, lane = t & 63;
    const int wm = wid & 1, wn = wid >> 1;
    const int lg = lane >> 4, l15 = lane & 15;

    f32x4 acc[2][4];
    #pragma unroll
    for (int i = 0; i < 2; i++)
        #pragma unroll
        for (int j = 0; j < 4; j++) acc[i][j] = (f32x4){0.f, 0.f, 0.f, 0.f};

    const int arow = t >> 2, achk = t & 3;
    const int brow = t >> 1, bhalf = t & 1;

    for (int k0 = 0; k0 < KDIM; k0 += 32) {
        __syncthreads();
        *(uint4*)(&As[arow][achk * 8]) =
            *(const uint4*)(A + (size_t)(row0 + arow) * KDIM + k0 + achk * 8);
        const unsigned short* bsrc = BT + (size_t)(col0 + brow) * KDIM + k0 + bhalf * 16;
        *(uint4*)(&Bs[brow][bhalf * 16])     = *(const uint4*)(bsrc);
        *(uint4*)(&Bs[brow][bhalf * 16 + 8]) = *(const uint4*)(bsrc + 8);
        __syncthreads();
        bf16x8 af[2], bfr[4];
        #pragma unroll
        for (int fm = 0; fm < 2; fm++)
            af[fm] = *(const bf16x8*)(&As[wm * 32 + fm * 16 + l15][lg * 8]);
        #pragma unroll
        for (int fn = 0; fn < 4; fn++)
            bfr[fn] = *(const bf16x8*)(&Bs[wn * 64 + fn * 16 + l15][lg * 8]);
        #pragma unroll
        for (int fm = 0; fm < 2; fm++)
            #pragma unroll
            for (int fn = 0; fn < 4; fn++)
                acc[fm][fn] = __builtin_amdgcn_mfma_f32_16x16x32_bf16(
                    af[fm], bfr[fn], acc[fm][fn], 0, 0, 0);
    }
    #pragma unroll
    for (int fm = 0; fm < 2; fm++)
        #pragma unroll
        for (int fn = 0; fn < 4; fn++) {
            int col = col0 + wn * 64 + fn * 16 + l15;
            float bvv = bias[col];
            #pragma unroll
            for (int r = 0; r < 4; r++) {
                int row = row0 + wm * 32 + fm * 16 + lg * 4 + r;
                float v = acc[fm][fn][r] + bvv;
                if (RELU) v = fmaxf(v, 0.f);
                v *= scale;
                if (OUTBF) ((unsigned short*)Cout)[(size_t)row * 256 + col] = f2bf(v);
                else       ((float*)Cout)[(size_t)row * 256 + col] = v;
            }
        }
}

__global__ __launch_bounds__(256, 2) void gemm512_kernel(
    const unsigned short* __restrict__ A,
    const unsigned short* __restrict__ BT,
    const float* __restrict__ bias,
    unsigned short* __restrict__ Cout)
{
    gemm_body<512, 1, 1>(A, BT, bias, (void*)Cout, 1.0f);
}

// ---------------- Vw body: Vw[row][h] = X[row]·Wvw[:,h] + bvw[h]
static __device__ __forceinline__ void vw_body(
    const unsigned short* __restrict__ Xbf,
    const float* __restrict__ Wvw,
    const float* __restrict__ bvw,
    float* __restrict__ Vw)
{
    __shared__ float sW[2048];
    __shared__ float sb[8];
    int t = threadIdx.x;
    #pragma unroll
    for (int i = 0; i < 8; i++) sW[i * 256 + t] = Wvw[i * 256 + t];
    if (t < 8) sb[t] = bvw[t];
    __syncthreads();
    int row = blockIdx.x * 256 + t;
    float acc[8];
    #pragma unroll
    for (int h = 0; h < 8; h++) acc[h] = sb[h];
    for (int d0 = 0; d0 < 32; d0++) {
        bf16x8 x = *(const bf16x8*)(Xbf + (size_t)row * 256 + d0 * 8);
        #pragma unroll
        for (int j = 0; j < 8; j++) {
            float xf = bf2f((unsigned short)x[j]);
            #pragma unroll
            for (int h = 0; h < 8; h++) acc[h] += xf * sW[(d0 * 8 + j) * 8 + h];
        }
    }
    *(float4*)(Vw + (size_t)row * 8)     = make_float4(acc[0], acc[1], acc[2], acc[3]);
    *(float4*)(Vw + (size_t)row * 8 + 4) = make_float4(acc[4], acc[5], acc[6], acc[7]);
}

// ---------------- fused Q-GEMM / K-GEMM / Vw in one launch (z selects)
__global__ __launch_bounds__(256, 2) void gemmQKV_kernel(
    const unsigned short* __restrict__ qbf,
    const unsigned short* __restrict__ WTq,
    const float* __restrict__ bq,
    unsigned short* __restrict__ Qbf,
    const unsigned short* __restrict__ Xbf,
    const unsigned short* __restrict__ WTk,
    const float* __restrict__ bk,
    unsigned short* __restrict__ Kbf,
    const float* __restrict__ Wvw,
    const float* __restrict__ bvw,
    float* __restrict__ Vw)
{
    if (blockIdx.z == 0) {
        gemm_body<256, 0, 1>(qbf, WTq, bq, (void*)Qbf, 0.17677669529663687f);
    } else if (blockIdx.z == 1) {
        gemm_body<256, 0, 1>(Xbf, WTk, bk, (void*)Kbf, 1.0f);
    } else {
        if (blockIdx.x >= 64 || blockIdx.y != 0) return;
        vw_body(Xbf, Wvw, bvw, Vw);
    }
}

// ---------------- attnD: denominator partials -> atomicAdd into den workspace
// grid 2048: id -> b (32) x qt (16) x kc (4); 256 threads = 4 waves
__global__ __launch_bounds__(256, 8) void attnD_kernel(
    const unsigned short* __restrict__ Qbf,
    const unsigned short* __restrict__ Kbf,
    const float* __restrict__ rel,
    const float* __restrict__ tsp,
    float* __restrict__ denp,    // [32][8][512]
    float* __restrict__ dent,    // [32][512]
    float* __restrict__ denr)    // [32][512]
{
    const int t = threadIdx.x;
    const int id = blockIdx.x;
    const int b  = id >> 6;
    const int qt = (id >> 2) & 15;
    const int kc = id & 3;
    const int q0 = qt * 32;
    const int w = t >> 6, lane = t & 63;
    const int l15 = lane & 15, lg = lane >> 4;

    // Q fragments for this wave's 2 heads
    bf16x8 aq[2][2];
    #pragma unroll
    for (int hh = 0; hh < 2; hh++)
        #pragma unroll
        for (int mf = 0; mf < 2; mf++)
            aq[hh][mf] = *(const bf16x8*)(Qbf +
                (size_t)(b * SEQ + q0 + mf * 16 + l15) * EMB + (2 * w + hh) * 32 + lg * 8);

    float dp[2][2][4] = {};
    #pragma unroll 1
    for (int i = 0; i < 4; i++) {
        const int kt = kc + 4 * i;
        if (kt > qt) break;
        const int k0 = kt * 32;
        #pragma unroll
        for (int hh = 0; hh < 2; hh++) {
            #pragma unroll
            for (int nf = 0; nf < 2; nf++) {
                bf16x8 bk = *(const bf16x8*)(Kbf +
                    (size_t)(b * SEQ + k0 + nf * 16 + l15) * EMB + (2 * w + hh) * 32 + lg * 8);
                const int kcol = k0 + nf * 16 + l15;
                #pragma unroll
                for (int mf = 0; mf < 2; mf++) {
                    f32x4 am = __builtin_amdgcn_mfma_f32_16x16x32_bf16(
                        aq[hh][mf], bk, (f32x4){0, 0, 0, 0}, 0, 0, 0);
                    #pragma unroll
                    for (int r = 0; r < 4; r++) {
                        const int qrow = q0 + mf * 16 + lg * 4 + r;
                        dp[hh][mf][r] += (kcol <= qrow) ? __expf(am[r]) : 0.f;
                    }
                }
            }
        }
    }

    // rel/ts: wave w handles tile kc + 4*w
    float dt[2][4] = {}, dr[2][4] = {};
    {
        const int kt2 = kc + 4 * w;
        if (kt2 <= qt) {
            const int k0 = kt2 * 32;
            #pragma unroll
            for (int mf = 0; mf < 2; mf++)
                #pragma unroll
                for (int r = 0; r < 4; r++) {
                    const int qrow = q0 + mf * 16 + lg * 4 + r;
                    const size_t base = ((size_t)(b * SEQ) + qrow) * SEQ + k0 + l15;
                    #pragma unroll
                    for (int nf = 0; nf < 2; nf++) {
                        const int kcol = k0 + nf * 16 + l15;
                        const bool va = kcol <= qrow;
                        float tv = tsp[base + nf * 16];
                        float rv = rel[base + nf * 16];
                        dt[mf][r] += va ? __expf(__expf(-fabsf(tv))) : 0.f;
                        dr[mf][r] += (va && rv != 0.f) ? __expf(rv) : 0.f;
                    }
                }
        }
    }

    // shfl-reduce over the 16 key lanes, then atomicAdd partials
    #pragma unroll
    for (int hh = 0; hh < 2; hh++)
        #pragma unroll
        for (int mf = 0; mf < 2; mf++)
            #pragma unroll
            for (int r = 0; r < 4; r++) {
                float v = dp[hh][mf][r];
                v += __shfl_xor(v, 1); v += __shfl_xor(v, 2);
                v += __shfl_xor(v, 4); v += __shfl_xor(v, 8);
                if (l15 == 0)
                    atomicAdd(&denp[((size_t)(b * NHEAD + 2 * w + hh)) * SEQ
                                    + q0 + mf * 16 + lg * 4 + r], v);
            }
    #pragma unroll
    for (int mf = 0; mf < 2; mf++)
        #pragma unroll
        for (int r = 0; r < 4; r++) {
            float v = dt[mf][r];
            v += __shfl_xor(v, 1); v += __shfl_xor(v, 2);
            v += __shfl_xor(v, 4); v += __shfl_xor(v, 8);
            float u = dr[mf][r];
            u += __shfl_xor(u, 1); u += __shfl_xor(u, 2);
            u += __shfl_xor(u, 4); u += __shfl_xor(u, 8);
            if (l15 == 0) {
                const int qrow = q0 + mf * 16 + lg * 4 + r;
                atomicAdd(&dent[b * SEQ + qrow], v);
                atomicAdd(&denr[b * SEQ + qrow], u);
            }
        }
}

// ---------------- attnW v4: fused blend+scores; block = (b, head, 16-row strip, ALL k)
// grid 8192: id -> strip heavy-first (32) x b (32) x h (8); 256 threads = 4 waves
__global__ __launch_bounds__(256, 8) void attnW_kernel(
    const unsigned short* __restrict__ Qbf,
    const unsigned short* __restrict__ Kbf,
    const float* __restrict__ Vw,
    const float* __restrict__ rel,
    const float* __restrict__ tsp,
    const float* __restrict__ denp,
    const float* __restrict__ dent,
    const float* __restrict__ denr,
    const float* __restrict__ pl1,
    const float* __restrict__ pl2,
    float* __restrict__ logits,
    float* __restrict__ attn)
{
    __shared__ float sT[16][260];
    __shared__ float slog[4][16];

    const int t = threadIdx.x;
    const int id = blockIdx.x;
    const int qt16 = 31 - (id >> 8);      // heavy strips dispatched first
    const int b = (id >> 3) & 31;
    const int h = id & 7;                 // h innermost: 8 neighbors share rel/ts rows
    const int q0 = qt16 * 16;
    const int qmax = q0 + 15;

    const int w = t >> 6, lane = t & 63;
    const int l15 = lane & 15, lg = lane >> 4;

    const float l1 = pl1[0], l2 = pl2[0];
    const float cp = (1.f - l1) * (1.f - l2);
    const float ct = (1.f - l1) * l2;
    const float cr = l1;

    // blend/write geometry: row = t>>4, 4 float4s at 64-float steps
    const int wrow = t >> 4;
    const int wcol = (t & 15) * 4;
    const int qrow_w = q0 + wrow;
    const float dtv = dent[b * SEQ + qrow_w];
    const float drv = denr[b * SEQ + qrow_w];
    const float ctt = ct / dtv;
    const float crr = drv > 0.f ? cr / drv : 0.f;

    float* arow_base = attn + ((size_t)((b * NHEAD + h) * SEQ) + q0 + wrow) * SEQ;
    const size_t rbase = ((size_t)(b * SEQ) + qrow_w) * SEQ;

    // Q fragment: rows q0+l15, dims h*32 + lg*8
    bf16x8 aq = *(const bf16x8*)(Qbf + (size_t)(b * SEQ + q0 + l15) * EMB + h * 32 + lg * 8);

    float invp[4];
    #pragma unroll
    for (int r = 0; r < 4; r++)
        invp[r] = 1.f / denp[((size_t)(b * NHEAD + h)) * SEQ + q0 + lg * 4 + r];

    float plog[4] = {0.f, 0.f, 0.f, 0.f};
    const f32x4 z4 = (f32x4){0.f, 0.f, 0.f, 0.f};

    for (int pass = 0; pass < 2; pass++) {
        const int c0 = pass * 256;
        if (c0 > qmax) {   // whole pass strictly future: direct nt zero stores
            #pragma unroll
            for (int s = 0; s < 4; s++) {
                const int cf = wcol + s * 64;
                __builtin_nontemporal_store(z4, (f32x4*)(arow_base + c0 + cf));
            }
            continue;      // block-uniform branch, barrier-safe
        }
        // blend term (time+rel softmax) computed in-place into LDS
        #pragma unroll
        for (int s = 0; s < 4; s++) {
            const int cf = wcol + s * 64;
            const int kbase = c0 + cf;
            if (kbase > qrow_w) {
                *(f32x4*)(&sT[wrow][cf]) = z4;
            } else {
                float4 tv4 = *(const float4*)(tsp + rbase + kbase);
                float4 rv4 = *(const float4*)(rel + rbase + kbase);
                const float* tvp = &tv4.x;
                const float* rvp = &rv4.x;
                f32x4 o;
                #pragma unroll
                for (int j = 0; j < 4; j++) {
                    const bool va = (kbase + j) <= qrow_w;
                    float e_t = va ? __expf(__expf(-fabsf(tvp[j]))) * ctt : 0.f;
                    float e_r = (va && rvp[j] != 0.f) ? __expf(rvp[j]) * crr : 0.f;
                    o[j] = e_t + e_r;
                }
                *(f32x4*)(&sT[wrow][cf]) = o;
            }
        }
        __syncthreads();
        // MFMA scores added on top; wave w handles kt = w and w+4
        #pragma unroll
        for (int ki = 0; ki < 2; ki++) {
            const int kt = w + ki * 4;
            const int k0 = c0 + kt * 32;
            if (k0 <= qmax) {
                #pragma unroll
                for (int nf = 0; nf < 2; nf++) {
                    const int kcol = k0 + nf * 16 + l15;
                    const int lcol = kt * 32 + nf * 16 + l15;
                    bf16x8 bk = *(const bf16x8*)(Kbf +
                        (size_t)(b * SEQ + kcol) * EMB + h * 32 + lg * 8);
                    const float vwv = Vw[(size_t)(b * SEQ + kcol) * 8 + h];
                    f32x4 am = __builtin_amdgcn_mfma_f32_16x16x32_bf16(
                        aq, bk, (f32x4){0.f, 0.f, 0.f, 0.f}, 0, 0, 0);
                    #pragma unroll
                    for (int r = 0; r < 4; r++) {
                        const int qloc = lg * 4 + r;
                        if (kcol <= q0 + qloc) {
                            float a = fmaf(cp * __expf(am[r]), invp[r], sT[qloc][lcol]);
                            sT[qloc][lcol] = a;
                            plog[r] = fmaf(a, vwv, plog[r]);
                        }
                    }
                }
            }
        }
        __syncthreads();
        // writeback: 16 full rows, 256B-contiguous per 16-lane group, nontemporal
        #pragma unroll
        for (int s = 0; s < 4; s++) {
            const int cf = wcol + s * 64;
            f32x4 v = *(f32x4*)(&sT[wrow][cf]);
            __builtin_nontemporal_store(v, (f32x4*)(arow_base + c0 + cf));
        }
        __syncthreads();
    }

    // logits partials: reduce over 16 key lanes, cross-wave via LDS, 1 atomic/row
    #pragma unroll
    for (int r = 0; r < 4; r++) {
        float v = plog[r];
        v += __shfl_xor(v, 1); v += __shfl_xor(v, 2);
        v += __shfl_xor(v, 4); v += __shfl_xor(v, 8);
        if (l15 == 0) slog[w][lg * 4 + r] = v;
    }
    __syncthreads();
    if (t < 16)
        atomicAdd(&logits[b * SEQ + q0 + t],
                  slog[0][t] + slog[1][t] + slog[2][t] + slog[3][t]);
}

// ---------------- host launch ----------------
extern "C" void kernel_launch(void* const* d_in, const int* in_sizes, int n_in,
                              void* d_out, int out_size, void* d_ws, size_t ws_size,
                              hipStream_t stream)
{
    (void)in_sizes; (void)n_in; (void)out_size; (void)ws_size;
    const int*   item_inputs  = (const int*)d_in[0];
    const int*   label_inputs = (const int*)d_in[1];
    const int*   item_ids     = (const int*)d_in[2];
    const float* rel   = (const float*)d_in[3];
    const float* tsp   = (const float*)d_in[4];
    const float* emb   = (const float*)d_in[5];
    const float* W_in  = (const float*)d_in[6];
    const float* b_in  = (const float*)d_in[7];
    const float* Wq    = (const float*)d_in[8];
    const float* bq    = (const float*)d_in[9];
    const float* Wk    = (const float*)d_in[10];
    const float* bk    = (const float*)d_in[11];
    const float* Wv    = (const float*)d_in[12];
    const float* bv    = (const float*)d_in[13];
    const float* Wout  = (const float*)d_in[14];
    const float* bout  = (const float*)d_in[15];
    const float* l1    = (const float*)d_in[16];
    const float* l2    = (const float*)d_in[17];

    const size_t R = 16384;
    char* w = (char*)d_ws;
    unsigned short* Abig = (unsigned short*)w; w += R * 512 * 2;
    unsigned short* qbf  = (unsigned short*)w; w += R * 256 * 2;
    unsigned short* WTin = (unsigned short*)w; w += (size_t)256 * 512 * 2;
    unsigned short* WTq  = (unsigned short*)w; w += (size_t)256 * 256 * 2;
    unsigned short* WTk  = (unsigned short*)w; w += (size_t)256 * 256 * 2;
    unsigned short* Xbf  = (unsigned short*)w; w += R * 256 * 2;
    unsigned short* Qbf  = (unsigned short*)w; w += R * 256 * 2;
    unsigned short* Kbf  = (unsigned short*)w; w += R * 256 * 2;
    float* Wvw  = (float*)w; w += 2048 * 4;
    float* Vw   = (float*)w; w += R * 8 * 4;
    float* bvw  = (float*)w; w += 256;          // 8 floats + pad
    float* denp = (float*)w; w += (size_t)32 * NHEAD * SEQ * 4;   // 512 KB
    float* dent = (float*)w; w += (size_t)32 * SEQ * 4;           // 64 KB
    float* denr = (float*)w; w += (size_t)32 * SEQ * 4;           // 64 KB

    prep_kernel<<<dim3(4096), dim3(256), 0, stream>>>(
        item_inputs, label_inputs, item_ids, emb, Abig, qbf);
    // wcombo also zeroes denp/dent/denr (contiguous 163840 floats) and inits logits
    wcombo_kernel<<<dim3(1737), dim3(256), 0, stream>>>(
        W_in, Wq, Wk, Wv, Wout, bv, bout, WTin, WTq, WTk, Wvw, bvw,
        (float*)d_out, denp);

    gemm512_kernel<<<dim3(256, 2), dim3(256), 0, stream>>>(Abig, WTin, b_in, Xbf);
    gemmQKV_kernel<<<dim3(256, 2, 3), dim3(256), 0, stream>>>(
        qbf, WTq, bq, Qbf, Xbf, WTk, bk, Kbf, Wvw, bvw, Vw);

    float* logits = (float*)d_out;
    float* attnp  = (float*)d_out + 16384;
    attnD_kernel<<<dim3(2048), dim3(256), 0, stream>>>(
        Qbf, Kbf, rel, tsp, denp, dent, denr);
    attnW_kernel<<<dim3(8192), dim3(256), 0, stream>>>(
        Qbf, Kbf, Vw, rel, tsp, denp, dent, denr, l1, l2, logits, attnp);
}

// Round 11
// 177.500 us; speedup vs baseline: 2.2067x; 1.0240x over previous
//
#include <hip/hip_runtime.h>
#include <hip/hip_bf16.h>

#define SEQ 512
#define EMB 256
#define NHEAD 8
#define HD 32

using bf16x8 = __attribute__((ext_vector_type(8))) short;
using f32x4  = __attribute__((ext_vector_type(4))) float;

static __device__ __forceinline__ unsigned short f2bf(float x) {
    union { float f; unsigned int u; } v; v.f = x;
    unsigned int r = v.u + 0x7FFFu + ((v.u >> 16) & 1u);
    return (unsigned short)(r >> 16);
}
static __device__ __forceinline__ float bf2f(unsigned short v) {
    union { unsigned int u; float f; } w; w.u = ((unsigned int)v) << 16; return w.f;
}

// ---------------- L1: prep (gather+concat) || wcombo (weights+init) || dent/denr
// grid 6217: [0,4096) prep; [4096,5705) wcombo; [5705,6217) dentr
__global__ __launch_bounds__(256) void fused_prep_kernel(
    const int* __restrict__ item_inputs,
    const int* __restrict__ label_inputs,
    const int* __restrict__ item_ids,
    const float* __restrict__ embeds,
    const float* __restrict__ W_in,
    const float* __restrict__ Wq,
    const float* __restrict__ Wk,
    const float* __restrict__ Wv,
    const float* __restrict__ Wout,
    const float* __restrict__ bv,
    const float* __restrict__ bout,
    const float* __restrict__ rel,
    const float* __restrict__ tsp,
    unsigned short* __restrict__ Abig,   // 16384 x 512 bf16
    unsigned short* __restrict__ qbf,    // 16384 x 256 bf16
    unsigned short* __restrict__ WTin,   // 256 x 512
    unsigned short* __restrict__ WTq,    // 256 x 256
    unsigned short* __restrict__ WTk,    // 256 x 256
    float* __restrict__ Wvw,             // 256 x 8
    float* __restrict__ bvw,             // 8
    float* __restrict__ logits,          // init to bout
    float* __restrict__ denp,            // 131072 floats -> zero
    float* __restrict__ dent,            // [32][512] written directly
    float* __restrict__ denr)            // [32][512] written directly
{
    const int bid = blockIdx.x;
    const int t = threadIdx.x;

    if (bid < 4096) {            // ---- prep ----
        int r = bid * 4 + (t >> 6);
        int j = (t & 63) * 4;
        int item = item_inputs[r];
        int lab  = label_inputs[r];
        int qid  = item_ids[r];
        float4 e4 = *(const float4*)(embeds + (size_t)item * EMB + j);
        ushort4 on  = make_ushort4(f2bf(e4.x), f2bf(e4.y), f2bf(e4.z), f2bf(e4.w));
        ushort4 off = make_ushort4(0, 0, 0, 0);
        *(ushort4*)(Abig + (size_t)r * 512 + j)       = lab ? on : off;
        *(ushort4*)(Abig + (size_t)r * 512 + 256 + j) = lab ? off : on;
        float4 q4 = *(const float4*)(embeds + (size_t)qid * EMB + j);
        *(ushort4*)(qbf + (size_t)r * 256 + j) =
            make_ushort4(f2bf(q4.x), f2bf(q4.y), f2bf(q4.z), f2bf(q4.w));
    } else if (bid < 5705) {     // ---- wcombo ----
        int idx = (bid - 4096) * 256 + t;
        if (idx < 131072) {                       // WTin[n][k] = W_in[k][n], K=512
            int n = idx >> 9, k = idx & 511;
            WTin[idx] = f2bf(W_in[(size_t)k * 256 + n]);
        } else if (idx < 196608) {                // WTq
            int i = idx - 131072;
            int n = i >> 8, k = i & 255;
            WTq[i] = f2bf(Wq[(size_t)k * 256 + n]);
        } else if (idx < 262144) {                // WTk
            int i = idx - 196608;
            int n = i >> 8, k = i & 255;
            WTk[i] = f2bf(Wk[(size_t)k * 256 + n]);
        } else if (idx < 264192) {                // Wvw
            int i = idx - 262144;
            int c = i >> 3, h = i & 7;
            float s = 0.f;
            #pragma unroll
            for (int d = 0; d < 32; d++)
                s += Wv[(size_t)c * 256 + h * 32 + d] * Wout[h * 32 + d];
            Wvw[i] = s;
        } else if (idx < 264200) {                // bvw
            int h = idx - 264192;
            float s = 0.f;
            #pragma unroll
            for (int d = 0; d < 32; d++) s += bv[h * 32 + d] * Wout[h * 32 + d];
            bvw[h] = s;
        } else if (idx < 280584) {                // logits init = bout
            logits[idx - 264200] = bout[0];
        } else if (idx < 411656) {                // zero denp
            denp[idx - 280584] = 0.f;
        }
    } else {                     // ---- dentr: dent/denr rows, direct write ----
        const int id2 = bid - 5705;
        const int b = id2 >> 4;
        const int qt = id2 & 15;
        const int q0 = qt * 32;
        const int row = t >> 3;           // 32 rows per block
        const int lane8 = t & 7;
        const int qrow = q0 + row;
        const size_t base = ((size_t)(b * SEQ) + qrow) * SEQ;
        float dt = 0.f, dr = 0.f;
        for (int k4 = lane8 * 4; k4 <= qrow; k4 += 32) {
            float4 tv4 = *(const float4*)(tsp + base + k4);
            float4 rv4 = *(const float4*)(rel + base + k4);
            const float* tvp = &tv4.x;
            const float* rvp = &rv4.x;
            #pragma unroll
            for (int j = 0; j < 4; j++) {
                const bool va = (k4 + j) <= qrow;
                dt += va ? __expf(__expf(-fabsf(tvp[j]))) : 0.f;
                dr += (va && rvp[j] != 0.f) ? __expf(rvp[j]) : 0.f;
            }
        }
        dt += __shfl_xor(dt, 1); dt += __shfl_xor(dt, 2); dt += __shfl_xor(dt, 4);
        dr += __shfl_xor(dr, 1); dr += __shfl_xor(dr, 2); dr += __shfl_xor(dr, 4);
        if (lane8 == 0) {
            dent[b * SEQ + qrow] = dt;
            denr[b * SEQ + qrow] = dr;
        }
    }
}

// ---------------- MFMA GEMM body: C(M x 256) = A(M x KDIM) * BT^T + bias
template<int KDIM, int RELU, int OUTBF>
static __device__ __forceinline__ void gemm_body(
    const unsigned short* __restrict__ A,
    const unsigned short* __restrict__ BT,
    const float* __restrict__ bias,
    void* __restrict__ Cout, float scale)
{
    __shared__ unsigned short As[64][40];
    __shared__ unsigned short Bs[128][40];
    const int t = threadIdx.x;
    const int row0 = blockIdx.x * 64;
    const int col0 = blockIdx.y * 128;
    const int wid = t >> 6, lane = t & 63;
    const int wm = wid & 1, wn = wid >> 1;
    const int lg = lane >> 4, l15 = lane & 15;

    f32x4 acc[2][4];
    #pragma unroll
    for (int i = 0; i < 2; i++)
        #pragma unroll
        for (int j = 0; j < 4; j++) acc[i][j] = (f32x4){0.f, 0.f, 0.f, 0.f};

    const int arow = t >> 2, achk = t & 3;
    const int brow = t >> 1, bhalf = t & 1;

    for (int k0 = 0; k0 < KDIM; k0 += 32) {
        __syncthreads();
        *(uint4*)(&As[arow][achk * 8]) =
            *(const uint4*)(A + (size_t)(row0 + arow) * KDIM + k0 + achk * 8);
        const unsigned short* bsrc = BT + (size_t)(col0 + brow) * KDIM + k0 + bhalf * 16;
        *(uint4*)(&Bs[brow][bhalf * 16])     = *(const uint4*)(bsrc);
        *(uint4*)(&Bs[brow][bhalf * 16 + 8]) = *(const uint4*)(bsrc + 8);
        __syncthreads();
        bf16x8 af[2], bfr[4];
        #pragma unroll
        for (int fm = 0; fm < 2; fm++)
            af[fm] = *(const bf16x8*)(&As[wm * 32 + fm * 16 + l15][lg * 8]);
        #pragma unroll
        for (int fn = 0; fn < 4; fn++)
            bfr[fn] = *(const bf16x8*)(&Bs[wn * 64 + fn * 16 + l15][lg * 8]);
        #pragma unroll
        for (int fm = 0; fm < 2; fm++)
            #pragma unroll
            for (int fn = 0; fn < 4; fn++)
                acc[fm][fn] = __builtin_amdgcn_mfma_f32_16x16x32_bf16(
                    af[fm], bfr[fn], acc[fm][fn], 0, 0, 0);
    }
    #pragma unroll
    for (int fm = 0; fm < 2; fm++)
        #pragma unroll
        for (int fn = 0; fn < 4; fn++) {
            int col = col0 + wn * 64 + fn * 16 + l15;
            float bvv = bias[col];
            #pragma unroll
            for (int r = 0; r < 4; r++) {
                int row = row0 + wm * 32 + fm * 16 + lg * 4 + r;
                float v = acc[fm][fn][r] + bvv;
                if (RELU) v = fmaxf(v, 0.f);
                v *= scale;
                if (OUTBF) ((unsigned short*)Cout)[(size_t)row * 256 + col] = f2bf(v);
                else       ((float*)Cout)[(size_t)row * 256 + col] = v;
            }
        }
}

// ---------------- L2: X-GEMM (K=512, relu) || Q-GEMM (independent) via z
__global__ __launch_bounds__(256, 2) void gemmA_kernel(
    const unsigned short* __restrict__ Abig,
    const unsigned short* __restrict__ WTin,
    const float* __restrict__ b_in,
    unsigned short* __restrict__ Xbf,
    const unsigned short* __restrict__ qbf,
    const unsigned short* __restrict__ WTq,
    const float* __restrict__ bq,
    unsigned short* __restrict__ Qbf)
{
    if (blockIdx.z == 0)
        gemm_body<512, 1, 1>(Abig, WTin, b_in, (void*)Xbf, 1.0f);
    else
        gemm_body<256, 0, 1>(qbf, WTq, bq, (void*)Qbf, 0.17677669529663687f);
}

// ---------------- Vw body: Vw[row][h] = X[row]·Wvw[:,h] + bvw[h]
static __device__ __forceinline__ void vw_body(
    const unsigned short* __restrict__ Xbf,
    const float* __restrict__ Wvw,
    const float* __restrict__ bvw,
    float* __restrict__ Vw)
{
    __shared__ float sW[2048];
    __shared__ float sb[8];
    int t = threadIdx.x;
    #pragma unroll
    for (int i = 0; i < 8; i++) sW[i * 256 + t] = Wvw[i * 256 + t];
    if (t < 8) sb[t] = bvw[t];
    __syncthreads();
    int row = blockIdx.x * 256 + t;
    float acc[8];
    #pragma unroll
    for (int h = 0; h < 8; h++) acc[h] = sb[h];
    for (int d0 = 0; d0 < 32; d0++) {
        bf16x8 x = *(const bf16x8*)(Xbf + (size_t)row * 256 + d0 * 8);
        #pragma unroll
        for (int j = 0; j < 8; j++) {
            float xf = bf2f((unsigned short)x[j]);
            #pragma unroll
            for (int h = 0; h < 8; h++) acc[h] += xf * sW[(d0 * 8 + j) * 8 + h];
        }
    }
    *(float4*)(Vw + (size_t)row * 8)     = make_float4(acc[0], acc[1], acc[2], acc[3]);
    *(float4*)(Vw + (size_t)row * 8 + 4) = make_float4(acc[4], acc[5], acc[6], acc[7]);
}

// ---------------- L3: K-GEMM || Vw via z
__global__ __launch_bounds__(256, 2) void gemmB_kernel(
    const unsigned short* __restrict__ Xbf,
    const unsigned short* __restrict__ WTk,
    const float* __restrict__ bk,
    unsigned short* __restrict__ Kbf,
    const float* __restrict__ Wvw,
    const float* __restrict__ bvw,
    float* __restrict__ Vw)
{
    if (blockIdx.z == 0) {
        gemm_body<256, 0, 1>(Xbf, WTk, bk, (void*)Kbf, 1.0f);
    } else {
        if (blockIdx.x >= 64 || blockIdx.y != 0) return;
        vw_body(Xbf, Wvw, bvw, Vw);
    }
}

// ---------------- L4: attnDp — denp only (no rel/ts)
// grid 2048: id -> b (32) x qt (16) x kc (4); 256 threads = 4 waves
__global__ __launch_bounds__(256, 8) void attnDp_kernel(
    const unsigned short* __restrict__ Qbf,
    const unsigned short* __restrict__ Kbf,
    float* __restrict__ denp)    // [32][8][512]
{
    const int t = threadIdx.x;
    const int id = blockIdx.x;
    const int b  = id >> 6;
    const int qt = (id >> 2) & 15;
    const int kc = id & 3;
    const int q0 = qt * 32;
    const int w = t >> 6, lane = t & 63;
    const int l15 = lane & 15, lg = lane >> 4;

    bf16x8 aq[2][2];
    #pragma unroll
    for (int hh = 0; hh < 2; hh++)
        #pragma unroll
        for (int mf = 0; mf < 2; mf++)
            aq[hh][mf] = *(const bf16x8*)(Qbf +
                (size_t)(b * SEQ + q0 + mf * 16 + l15) * EMB + (2 * w + hh) * 32 + lg * 8);

    float dp[2][2][4] = {};
    #pragma unroll 1
    for (int i = 0; i < 4; i++) {
        const int kt = kc + 4 * i;
        if (kt > qt) break;
        const int k0 = kt * 32;
        #pragma unroll
        for (int hh = 0; hh < 2; hh++) {
            #pragma unroll
            for (int nf = 0; nf < 2; nf++) {
                bf16x8 bk = *(const bf16x8*)(Kbf +
                    (size_t)(b * SEQ + k0 + nf * 16 + l15) * EMB + (2 * w + hh) * 32 + lg * 8);
                const int kcol = k0 + nf * 16 + l15;
                #pragma unroll
                for (int mf = 0; mf < 2; mf++) {
                    f32x4 am = __builtin_amdgcn_mfma_f32_16x16x32_bf16(
                        aq[hh][mf], bk, (f32x4){0, 0, 0, 0}, 0, 0, 0);
                    #pragma unroll
                    for (int r = 0; r < 4; r++) {
                        const int qrow = q0 + mf * 16 + lg * 4 + r;
                        dp[hh][mf][r] += (kcol <= qrow) ? __expf(am[r]) : 0.f;
                    }
                }
            }
        }
    }

    #pragma unroll
    for (int hh = 0; hh < 2; hh++)
        #pragma unroll
        for (int mf = 0; mf < 2; mf++)
            #pragma unroll
            for (int r = 0; r < 4; r++) {
                float v = dp[hh][mf][r];
                v += __shfl_xor(v, 1); v += __shfl_xor(v, 2);
                v += __shfl_xor(v, 4); v += __shfl_xor(v, 8);
                if (l15 == 0)
                    atomicAdd(&denp[((size_t)(b * NHEAD + 2 * w + hh)) * SEQ
                                    + q0 + mf * 16 + lg * 4 + r], v);
            }
}

// ---------------- L5: attnW v4 (unchanged from round 10)
// grid 8192: id -> strip heavy-first (32) x b (32) x h (8); 256 threads = 4 waves
__global__ __launch_bounds__(256, 8) void attnW_kernel(
    const unsigned short* __restrict__ Qbf,
    const unsigned short* __restrict__ Kbf,
    const float* __restrict__ Vw,
    const float* __restrict__ rel,
    const float* __restrict__ tsp,
    const float* __restrict__ denp,
    const float* __restrict__ dent,
    const float* __restrict__ denr,
    const float* __restrict__ pl1,
    const float* __restrict__ pl2,
    float* __restrict__ logits,
    float* __restrict__ attn)
{
    __shared__ float sT[16][260];
    __shared__ float slog[4][16];

    const int t = threadIdx.x;
    const int id = blockIdx.x;
    const int qt16 = 31 - (id >> 8);      // heavy strips dispatched first
    const int b = (id >> 3) & 31;
    const int h = id & 7;                 // h innermost: 8 neighbors share rel/ts rows
    const int q0 = qt16 * 16;
    const int qmax = q0 + 15;

    const int w = t >> 6, lane = t & 63;
    const int l15 = lane & 15, lg = lane >> 4;

    const float l1 = pl1[0], l2 = pl2[0];
    const float cp = (1.f - l1) * (1.f - l2);
    const float ct = (1.f - l1) * l2;
    const float cr = l1;

    const int wrow = t >> 4;
    const int wcol = (t & 15) * 4;
    const int qrow_w = q0 + wrow;
    const float dtv = dent[b * SEQ + qrow_w];
    const float drv = denr[b * SEQ + qrow_w];
    const float ctt = ct / dtv;
    const float crr = drv > 0.f ? cr / drv : 0.f;

    float* arow_base = attn + ((size_t)((b * NHEAD + h) * SEQ) + q0 + wrow) * SEQ;
    const size_t rbase = ((size_t)(b * SEQ) + qrow_w) * SEQ;

    bf16x8 aq = *(const bf16x8*)(Qbf + (size_t)(b * SEQ + q0 + l15) * EMB + h * 32 + lg * 8);

    float invp[4];
    #pragma unroll
    for (int r = 0; r < 4; r++)
        invp[r] = 1.f / denp[((size_t)(b * NHEAD + h)) * SEQ + q0 + lg * 4 + r];

    float plog[4] = {0.f, 0.f, 0.f, 0.f};
    const f32x4 z4 = (f32x4){0.f, 0.f, 0.f, 0.f};

    for (int pass = 0; pass < 2; pass++) {
        const int c0 = pass * 256;
        if (c0 > qmax) {   // whole pass strictly future: direct nt zero stores
            #pragma unroll
            for (int s = 0; s < 4; s++) {
                const int cf = wcol + s * 64;
                __builtin_nontemporal_store(z4, (f32x4*)(arow_base + c0 + cf));
            }
            continue;      // block-uniform branch, barrier-safe
        }
        #pragma unroll
        for (int s = 0; s < 4; s++) {
            const int cf = wcol + s * 64;
            const int kbase = c0 + cf;
            if (kbase > qrow_w) {
                *(f32x4*)(&sT[wrow][cf]) = z4;
            } else {
                float4 tv4 = *(const float4*)(tsp + rbase + kbase);
                float4 rv4 = *(const float4*)(rel + rbase + kbase);
                const float* tvp = &tv4.x;
                const float* rvp = &rv4.x;
                f32x4 o;
                #pragma unroll
                for (int j = 0; j < 4; j++) {
                    const bool va = (kbase + j) <= qrow_w;
                    float e_t = va ? __expf(__expf(-fabsf(tvp[j]))) * ctt : 0.f;
                    float e_r = (va && rvp[j] != 0.f) ? __expf(rvp[j]) * crr : 0.f;
                    o[j] = e_t + e_r;
                }
                *(f32x4*)(&sT[wrow][cf]) = o;
            }
        }
        __syncthreads();
        #pragma unroll
        for (int ki = 0; ki < 2; ki++) {
            const int kt = w + ki * 4;
            const int k0 = c0 + kt * 32;
            if (k0 <= qmax) {
                #pragma unroll
                for (int nf = 0; nf < 2; nf++) {
                    const int kcol = k0 + nf * 16 + l15;
                    const int lcol = kt * 32 + nf * 16 + l15;
                    bf16x8 bk = *(const bf16x8*)(Kbf +
                        (size_t)(b * SEQ + kcol) * EMB + h * 32 + lg * 8);
                    const float vwv = Vw[(size_t)(b * SEQ + kcol) * 8 + h];
                    f32x4 am = __builtin_amdgcn_mfma_f32_16x16x32_bf16(
                        aq, bk, (f32x4){0.f, 0.f, 0.f, 0.f}, 0, 0, 0);
                    #pragma unroll
                    for (int r = 0; r < 4; r++) {
                        const int qloc = lg * 4 + r;
                        if (kcol <= q0 + qloc) {
                            float a = fmaf(cp * __expf(am[r]), invp[r], sT[qloc][lcol]);
                            sT[qloc][lcol] = a;
                            plog[r] = fmaf(a, vwv, plog[r]);
                        }
                    }
                }
            }
        }
        __syncthreads();
        #pragma unroll
        for (int s = 0; s < 4; s++) {
            const int cf = wcol + s * 64;
            f32x4 v = *(f32x4*)(&sT[wrow][cf]);
            __builtin_nontemporal_store(v, (f32x4*)(arow_base + c0 + cf));
        }
        __syncthreads();
    }

    #pragma unroll
    for (int r = 0; r < 4; r++) {
        float v = plog[r];
        v += __shfl_xor(v, 1); v += __shfl_xor(v, 2);
        v += __shfl_xor(v, 4); v += __shfl_xor(v, 8);
        if (l15 == 0) slog[w][lg * 4 + r] = v;
    }
    __syncthreads();
    if (t < 16)
        atomicAdd(&logits[b * SEQ + q0 + t],
                  slog[0][t] + slog[1][t] + slog[2][t] + slog[3][t]);
}

// ---------------- host launch ----------------
extern "C" void kernel_launch(void* const* d_in, const int* in_sizes, int n_in,
                              void* d_out, int out_size, void* d_ws, size_t ws_size,
                              hipStream_t stream)
{
    (void)in_sizes; (void)n_in; (void)out_size; (void)ws_size;
    const int*   item_inputs  = (const int*)d_in[0];
    const int*   label_inputs = (const int*)d_in[1];
    const int*   item_ids     = (const int*)d_in[2];
    const float* rel   = (const float*)d_in[3];
    const float* tsp   = (const float*)d_in[4];
    const float* emb   = (const float*)d_in[5];
    const float* W_in  = (const float*)d_in[6];
    const float* b_in  = (const float*)d_in[7];
    const float* Wq    = (const float*)d_in[8];
    const float* bq    = (const float*)d_in[9];
    const float* Wk    = (const float*)d_in[10];
    const float* bk    = (const float*)d_in[11];
    const float* Wv    = (const float*)d_in[12];
    const float* bv    = (const float*)d_in[13];
    const float* Wout  = (const float*)d_in[14];
    const float* bout  = (const float*)d_in[15];
    const float* l1    = (const float*)d_in[16];
    const float* l2    = (const float*)d_in[17];

    const size_t R = 16384;
    char* w = (char*)d_ws;
    unsigned short* Abig = (unsigned short*)w; w += R * 512 * 2;
    unsigned short* qbf  = (unsigned short*)w; w += R * 256 * 2;
    unsigned short* WTin = (unsigned short*)w; w += (size_t)256 * 512 * 2;
    unsigned short* WTq  = (unsigned short*)w; w += (size_t)256 * 256 * 2;
    unsigned short* WTk  = (unsigned short*)w; w += (size_t)256 * 256 * 2;
    unsigned short* Xbf  = (unsigned short*)w; w += R * 256 * 2;
    unsigned short* Qbf  = (unsigned short*)w; w += R * 256 * 2;
    unsigned short* Kbf  = (unsigned short*)w; w += R * 256 * 2;
    float* Wvw  = (float*)w; w += 2048 * 4;
    float* Vw   = (float*)w; w += R * 8 * 4;
    float* bvw  = (float*)w; w += 256;          // 8 floats + pad
    float* denp = (float*)w; w += (size_t)32 * NHEAD * SEQ * 4;   // 512 KB
    float* dent = (float*)w; w += (size_t)32 * SEQ * 4;           // 64 KB
    float* denr = (float*)w; w += (size_t)32 * SEQ * 4;           // 64 KB

    float* logits = (float*)d_out;
    float* attnp  = (float*)d_out + 16384;

    // L1: prep || wcombo (+denp zero, logits init) || dent/denr
    fused_prep_kernel<<<dim3(6217), dim3(256), 0, stream>>>(
        item_inputs, label_inputs, item_ids, emb,
        W_in, Wq, Wk, Wv, Wout, bv, bout, rel, tsp,
        Abig, qbf, WTin, WTq, WTk, Wvw, bvw, logits, denp, dent, denr);

    // L2: X-GEMM || Q-GEMM
    gemmA_kernel<<<dim3(256, 2, 2), dim3(256), 0, stream>>>(
        Abig, WTin, b_in, Xbf, qbf, WTq, bq, Qbf);

    // L3: K-GEMM || Vw
    gemmB_kernel<<<dim3(256, 2, 2), dim3(256), 0, stream>>>(
        Xbf, WTk, bk, Kbf, Wvw, bvw, Vw);

    // L4: denp
    attnDp_kernel<<<dim3(2048), dim3(256), 0, stream>>>(Qbf, Kbf, denp);

    // L5: fused attention write
    attnW_kernel<<<dim3(8192), dim3(256), 0, stream>>>(
        Qbf, Kbf, Vw, rel, tsp, denp, dent, denr, l1, l2, logits, attnp);
}

// Round 12
// 153.703 us; speedup vs baseline: 2.5484x; 1.1548x over previous
//
#include <hip/hip_runtime.h>
#include <hip/hip_bf16.h>

#define SEQ 512
#define EMB 256
#define NHEAD 8
#define HD 32

using bf16x8 = __attribute__((ext_vector_type(8))) short;
using f32x4  = __attribute__((ext_vector_type(4))) float;

static __device__ __forceinline__ unsigned short f2bf(float x) {
    union { float f; unsigned int u; } v; v.f = x;
    unsigned int r = v.u + 0x7FFFu + ((v.u >> 16) & 1u);
    return (unsigned short)(r >> 16);
}
static __device__ __forceinline__ float bf2f(unsigned short v) {
    union { unsigned int u; float f; } w; w.u = ((unsigned int)v) << 16; return w.f;
}

// ---------------- L1: prep (gather+concat) || wcombo (weights+init) || dent/denr
// grid 5705: [0,4096) prep; [4096,5193) wcombo; [5193,5705) dentr
__global__ __launch_bounds__(256) void fused_prep_kernel(
    const int* __restrict__ item_inputs,
    const int* __restrict__ label_inputs,
    const int* __restrict__ item_ids,
    const float* __restrict__ embeds,
    const float* __restrict__ W_in,
    const float* __restrict__ Wq,
    const float* __restrict__ Wk,
    const float* __restrict__ Wv,
    const float* __restrict__ Wout,
    const float* __restrict__ bv,
    const float* __restrict__ bout,
    const float* __restrict__ rel,
    const float* __restrict__ tsp,
    unsigned short* __restrict__ Abig,   // 16384 x 512 bf16
    unsigned short* __restrict__ qbf,    // 16384 x 256 bf16
    unsigned short* __restrict__ WTin,   // 256 x 512
    unsigned short* __restrict__ WTq,    // 256 x 256
    unsigned short* __restrict__ WTk,    // 256 x 256
    float* __restrict__ Wvw,             // 256 x 8
    float* __restrict__ bvw,             // 8
    float* __restrict__ logits,          // init to bout
    float* __restrict__ dent,            // [32][512] written directly
    float* __restrict__ denr)            // [32][512] written directly
{
    const int bid = blockIdx.x;
    const int t = threadIdx.x;

    if (bid < 4096) {            // ---- prep ----
        int r = bid * 4 + (t >> 6);
        int j = (t & 63) * 4;
        int item = item_inputs[r];
        int lab  = label_inputs[r];
        int qid  = item_ids[r];
        float4 e4 = *(const float4*)(embeds + (size_t)item * EMB + j);
        ushort4 on  = make_ushort4(f2bf(e4.x), f2bf(e4.y), f2bf(e4.z), f2bf(e4.w));
        ushort4 off = make_ushort4(0, 0, 0, 0);
        *(ushort4*)(Abig + (size_t)r * 512 + j)       = lab ? on : off;
        *(ushort4*)(Abig + (size_t)r * 512 + 256 + j) = lab ? off : on;
        float4 q4 = *(const float4*)(embeds + (size_t)qid * EMB + j);
        *(ushort4*)(qbf + (size_t)r * 256 + j) =
            make_ushort4(f2bf(q4.x), f2bf(q4.y), f2bf(q4.z), f2bf(q4.w));
    } else if (bid < 5193) {     // ---- wcombo ----
        int idx = (bid - 4096) * 256 + t;
        if (idx < 131072) {                       // WTin[n][k] = W_in[k][n], K=512
            int n = idx >> 9, k = idx & 511;
            WTin[idx] = f2bf(W_in[(size_t)k * 256 + n]);
        } else if (idx < 196608) {                // WTq
            int i = idx - 131072;
            int n = i >> 8, k = i & 255;
            WTq[i] = f2bf(Wq[(size_t)k * 256 + n]);
        } else if (idx < 262144) {                // WTk
            int i = idx - 196608;
            int n = i >> 8, k = i & 255;
            WTk[i] = f2bf(Wk[(size_t)k * 256 + n]);
        } else if (idx < 264192) {                // Wvw
            int i = idx - 262144;
            int c = i >> 3, h = i & 7;
            float s = 0.f;
            #pragma unroll
            for (int d = 0; d < 32; d++)
                s += Wv[(size_t)c * 256 + h * 32 + d] * Wout[h * 32 + d];
            Wvw[i] = s;
        } else if (idx < 264200) {                // bvw
            int h = idx - 264192;
            float s = 0.f;
            #pragma unroll
            for (int d = 0; d < 32; d++) s += bv[h * 32 + d] * Wout[h * 32 + d];
            bvw[h] = s;
        } else if (idx < 280584) {                // logits init = bout
            logits[idx - 264200] = bout[0];
        }
    } else {                     // ---- dentr: dent/denr rows, direct write ----
        const int id2 = bid - 5193;
        const int b = id2 >> 4;
        const int qt = id2 & 15;
        const int q0 = qt * 32;
        const int row = t >> 3;           // 32 rows per block
        const int lane8 = t & 7;
        const int qrow = q0 + row;
        const size_t base = ((size_t)(b * SEQ) + qrow) * SEQ;
        float dt = 0.f, dr = 0.f;
        for (int k4 = lane8 * 4; k4 <= qrow; k4 += 32) {
            float4 tv4 = *(const float4*)(tsp + base + k4);
            float4 rv4 = *(const float4*)(rel + base + k4);
            const float* tvp = &tv4.x;
            const float* rvp = &rv4.x;
            #pragma unroll
            for (int j = 0; j < 4; j++) {
                const bool va = (k4 + j) <= qrow;
                dt += va ? __expf(__expf(-fabsf(tvp[j]))) : 0.f;
                dr += (va && rvp[j] != 0.f) ? __expf(rvp[j]) : 0.f;
            }
        }
        dt += __shfl_xor(dt, 1); dt += __shfl_xor(dt, 2); dt += __shfl_xor(dt, 4);
        dr += __shfl_xor(dr, 1); dr += __shfl_xor(dr, 2); dr += __shfl_xor(dr, 4);
        if (lane8 == 0) {
            dent[b * SEQ + qrow] = dt;
            denr[b * SEQ + qrow] = dr;
        }
    }
}

// ---------------- MFMA GEMM body: C(M x 256) = A(M x KDIM) * BT^T + bias
template<int KDIM, int RELU, int OUTBF>
static __device__ __forceinline__ void gemm_body(
    const unsigned short* __restrict__ A,
    const unsigned short* __restrict__ BT,
    const float* __restrict__ bias,
    void* __restrict__ Cout, float scale)
{
    __shared__ unsigned short As[64][40];
    __shared__ unsigned short Bs[128][40];
    const int t = threadIdx.x;
    const int row0 = blockIdx.x * 64;
    const int col0 = blockIdx.y * 128;
    const int wid = t >> 6, lane = t & 63;
    const int wm = wid & 1, wn = wid >> 1;
    const int lg = lane >> 4, l15 = lane & 15;

    f32x4 acc[2][4];
    #pragma unroll
    for (int i = 0; i < 2; i++)
        #pragma unroll
        for (int j = 0; j < 4; j++) acc[i][j] = (f32x4){0.f, 0.f, 0.f, 0.f};

    const int arow = t >> 2, achk = t & 3;
    const int brow = t >> 1, bhalf = t & 1;

    for (int k0 = 0; k0 < KDIM; k0 += 32) {
        __syncthreads();
        *(uint4*)(&As[arow][achk * 8]) =
            *(const uint4*)(A + (size_t)(row0 + arow) * KDIM + k0 + achk * 8);
        const unsigned short* bsrc = BT + (size_t)(col0 + brow) * KDIM + k0 + bhalf * 16;
        *(uint4*)(&Bs[brow][bhalf * 16])     = *(const uint4*)(bsrc);
        *(uint4*)(&Bs[brow][bhalf * 16 + 8]) = *(const uint4*)(bsrc + 8);
        __syncthreads();
        bf16x8 af[2], bfr[4];
        #pragma unroll
        for (int fm = 0; fm < 2; fm++)
            af[fm] = *(const bf16x8*)(&As[wm * 32 + fm * 16 + l15][lg * 8]);
        #pragma unroll
        for (int fn = 0; fn < 4; fn++)
            bfr[fn] = *(const bf16x8*)(&Bs[wn * 64 + fn * 16 + l15][lg * 8]);
        #pragma unroll
        for (int fm = 0; fm < 2; fm++)
            #pragma unroll
            for (int fn = 0; fn < 4; fn++)
                acc[fm][fn] = __builtin_amdgcn_mfma_f32_16x16x32_bf16(
                    af[fm], bfr[fn], acc[fm][fn], 0, 0, 0);
    }
    #pragma unroll
    for (int fm = 0; fm < 2; fm++)
        #pragma unroll
        for (int fn = 0; fn < 4; fn++) {
            int col = col0 + wn * 64 + fn * 16 + l15;
            float bvv = bias[col];
            #pragma unroll
            for (int r = 0; r < 4; r++) {
                int row = row0 + wm * 32 + fm * 16 + lg * 4 + r;
                float v = acc[fm][fn][r] + bvv;
                if (RELU) v = fmaxf(v, 0.f);
                v *= scale;
                if (OUTBF) ((unsigned short*)Cout)[(size_t)row * 256 + col] = f2bf(v);
                else       ((float*)Cout)[(size_t)row * 256 + col] = v;
            }
        }
}

// ---------------- L2: X-GEMM (K=512, relu) || Q-GEMM (independent) via z
__global__ __launch_bounds__(256, 2) void gemmA_kernel(
    const unsigned short* __restrict__ Abig,
    const unsigned short* __restrict__ WTin,
    const float* __restrict__ b_in,
    unsigned short* __restrict__ Xbf,
    const unsigned short* __restrict__ qbf,
    const unsigned short* __restrict__ WTq,
    const float* __restrict__ bq,
    unsigned short* __restrict__ Qbf)
{
    if (blockIdx.z == 0)
        gemm_body<512, 1, 1>(Abig, WTin, b_in, (void*)Xbf, 1.0f);
    else
        gemm_body<256, 0, 1>(qbf, WTq, bq, (void*)Qbf, 0.17677669529663687f);
}

// ---------------- Vw body: Vw[row][h] = X[row]·Wvw[:,h] + bvw[h]
static __device__ __forceinline__ void vw_body(
    const unsigned short* __restrict__ Xbf,
    const float* __restrict__ Wvw,
    const float* __restrict__ bvw,
    float* __restrict__ Vw)
{
    __shared__ float sW[2048];
    __shared__ float sb[8];
    int t = threadIdx.x;
    #pragma unroll
    for (int i = 0; i < 8; i++) sW[i * 256 + t] = Wvw[i * 256 + t];
    if (t < 8) sb[t] = bvw[t];
    __syncthreads();
    int row = blockIdx.x * 256 + t;
    float acc[8];
    #pragma unroll
    for (int h = 0; h < 8; h++) acc[h] = sb[h];
    for (int d0 = 0; d0 < 32; d0++) {
        bf16x8 x = *(const bf16x8*)(Xbf + (size_t)row * 256 + d0 * 8);
        #pragma unroll
        for (int j = 0; j < 8; j++) {
            float xf = bf2f((unsigned short)x[j]);
            #pragma unroll
            for (int h = 0; h < 8; h++) acc[h] += xf * sW[(d0 * 8 + j) * 8 + h];
        }
    }
    *(float4*)(Vw + (size_t)row * 8)     = make_float4(acc[0], acc[1], acc[2], acc[3]);
    *(float4*)(Vw + (size_t)row * 8 + 4) = make_float4(acc[4], acc[5], acc[6], acc[7]);
}

// ---------------- L3: K-GEMM || Vw via z
__global__ __launch_bounds__(256, 2) void gemmB_kernel(
    const unsigned short* __restrict__ Xbf,
    const unsigned short* __restrict__ WTk,
    const float* __restrict__ bk,
    unsigned short* __restrict__ Kbf,
    const float* __restrict__ Wvw,
    const float* __restrict__ bvw,
    float* __restrict__ Vw)
{
    if (blockIdx.z == 0) {
        gemm_body<256, 0, 1>(Xbf, WTk, bk, (void*)Kbf, 1.0f);
    } else {
        if (blockIdx.x >= 64 || blockIdx.y != 0) return;
        vw_body(Xbf, Wvw, bvw, Vw);
    }
}

// ---------------- L4: attnW v5 — fully fused: scores+den (phase 1, LDS-stashed exp),
// normalize+blend+write+logits (phase 2). Block = (b, h, 16-row strip, ALL k).
// grid 8192: id -> strip heavy-first (32) x b (32) x h (8); 256 threads = 4 waves
__global__ __launch_bounds__(256, 4) void attnW_kernel(
    const unsigned short* __restrict__ Qbf,
    const unsigned short* __restrict__ Kbf,
    const float* __restrict__ Vw,
    const float* __restrict__ rel,
    const float* __restrict__ tsp,
    const float* __restrict__ dent,
    const float* __restrict__ denr,
    const float* __restrict__ pl1,
    const float* __restrict__ pl2,
    float* __restrict__ logits,
    float* __restrict__ attn)
{
    __shared__ float sP[16][516];   // exp(score), pad 516 -> 2-way bank alias (free)
    __shared__ float sVw[512];
    __shared__ float sden[4][16];

    const int t = threadIdx.x;
    const int id = blockIdx.x;
    const int qt16 = 31 - (id >> 8);      // heavy strips dispatched first
    const int b = (id >> 3) & 31;
    const int h = id & 7;                 // h innermost: 8 neighbors share rel/ts rows
    const int q0 = qt16 * 16;
    const int qmax = q0 + 15;

    const int w = t >> 6, lane = t & 63;
    const int l15 = lane & 15, lg = lane >> 4;

    const float l1 = pl1[0], l2 = pl2[0];
    const float cp = (1.f - l1) * (1.f - l2);
    const float ct = (1.f - l1) * l2;
    const float cr = l1;

    // stage Vw column h for this b
    sVw[t]       = Vw[((size_t)(b * SEQ) + t) * 8 + h];
    sVw[256 + t] = Vw[((size_t)(b * SEQ) + 256 + t) * 8 + h];

    // Q fragment: rows q0+l15, dims h*32 + lg*8
    bf16x8 aq = *(const bf16x8*)(Qbf + (size_t)(b * SEQ + q0 + l15) * EMB + h * 32 + lg * 8);

    // ---- phase 1: MFMA scores -> exp -> sP; per-row den partials ----
    float dp[4] = {0.f, 0.f, 0.f, 0.f};
    #pragma unroll
    for (int ki = 0; ki < 4; ki++) {
        const int kt = w + ki * 4;        // wave-uniform tile index 0..15
        const int k0 = kt * 32;
        if (k0 <= qmax) {
            #pragma unroll
            for (int nf = 0; nf < 2; nf++) {
                const int kcol = k0 + nf * 16 + l15;
                const int lcol = k0 + nf * 16 + l15;
                bf16x8 bk = *(const bf16x8*)(Kbf +
                    (size_t)(b * SEQ + kcol) * EMB + h * 32 + lg * 8);
                f32x4 am = __builtin_amdgcn_mfma_f32_16x16x32_bf16(
                    aq, bk, (f32x4){0.f, 0.f, 0.f, 0.f}, 0, 0, 0);
                #pragma unroll
                for (int r = 0; r < 4; r++) {
                    const int qloc = lg * 4 + r;
                    float e = (kcol <= q0 + qloc) ? __expf(am[r]) : 0.f;
                    sP[qloc][lcol] = e;
                    dp[r] += e;
                }
            }
        } else {
            #pragma unroll
            for (int nf = 0; nf < 2; nf++)
                #pragma unroll
                for (int r = 0; r < 4; r++)
                    sP[lg * 4 + r][k0 + nf * 16 + l15] = 0.f;
        }
    }
    #pragma unroll
    for (int r = 0; r < 4; r++) {
        float v = dp[r];
        v += __shfl_xor(v, 1); v += __shfl_xor(v, 2);
        v += __shfl_xor(v, 4); v += __shfl_xor(v, 8);
        if (l15 == 0) sden[w][lg * 4 + r] = v;
    }
    __syncthreads();

    // ---- phase 2: normalize + blend + nt write + logits ----
    const int wrow = t >> 4;
    const int wcol = (t & 15) * 4;
    const int qrow_w = q0 + wrow;
    const float den = sden[0][wrow] + sden[1][wrow] + sden[2][wrow] + sden[3][wrow];
    const float cpinv = cp / den;         // den>0: diagonal always valid
    const float dtv = dent[b * SEQ + qrow_w];
    const float drv = denr[b * SEQ + qrow_w];
    const float ctt = ct / dtv;
    const float crr = drv > 0.f ? cr / drv : 0.f;

    float* arow = attn + ((size_t)((b * NHEAD + h) * SEQ) + qrow_w) * SEQ;
    const size_t rbase = ((size_t)(b * SEQ) + qrow_w) * SEQ;
    const f32x4 z4 = (f32x4){0.f, 0.f, 0.f, 0.f};
    float plog = 0.f;

    #pragma unroll
    for (int s = 0; s < 8; s++) {
        const int c = wcol + s * 64;
        f32x4 o;
        if (c > qrow_w) {
            o = z4;
        } else {
            float4 tv4 = *(const float4*)(tsp + rbase + c);
            float4 rv4 = *(const float4*)(rel + rbase + c);
            const float* tvp = &tv4.x;
            const float* rvp = &rv4.x;
            #pragma unroll
            for (int j = 0; j < 4; j++) {
                const bool va = (c + j) <= qrow_w;
                float e_t = va ? __expf(__expf(-fabsf(tvp[j]))) * ctt : 0.f;
                float e_r = (va && rvp[j] != 0.f) ? __expf(rvp[j]) * crr : 0.f;
                float a = fmaf(sP[wrow][c + j], cpinv, e_t + e_r);  // sP=0 if invalid
                a = va ? a : 0.f;
                o[j] = a;
                plog = fmaf(a, sVw[c + j], plog);
            }
        }
        __builtin_nontemporal_store(o, (f32x4*)(arow + c));
    }

    // per-row logits: reduce over the 16 col-lanes, one atomic per row
    plog += __shfl_xor(plog, 1); plog += __shfl_xor(plog, 2);
    plog += __shfl_xor(plog, 4); plog += __shfl_xor(plog, 8);
    if ((t & 15) == 0)
        atomicAdd(&logits[b * SEQ + qrow_w], plog);
}

// ---------------- host launch ----------------
extern "C" void kernel_launch(void* const* d_in, const int* in_sizes, int n_in,
                              void* d_out, int out_size, void* d_ws, size_t ws_size,
                              hipStream_t stream)
{
    (void)in_sizes; (void)n_in; (void)out_size; (void)ws_size;
    const int*   item_inputs  = (const int*)d_in[0];
    const int*   label_inputs = (const int*)d_in[1];
    const int*   item_ids     = (const int*)d_in[2];
    const float* rel   = (const float*)d_in[3];
    const float* tsp   = (const float*)d_in[4];
    const float* emb   = (const float*)d_in[5];
    const float* W_in  = (const float*)d_in[6];
    const float* b_in  = (const float*)d_in[7];
    const float* Wq    = (const float*)d_in[8];
    const float* bq    = (const float*)d_in[9];
    const float* Wk    = (const float*)d_in[10];
    const float* bk    = (const float*)d_in[11];
    const float* Wv    = (const float*)d_in[12];
    const float* bv    = (const float*)d_in[13];
    const float* Wout  = (const float*)d_in[14];
    const float* bout  = (const float*)d_in[15];
    const float* l1    = (const float*)d_in[16];
    const float* l2    = (const float*)d_in[17];

    const size_t R = 16384;
    char* w = (char*)d_ws;
    unsigned short* Abig = (unsigned short*)w; w += R * 512 * 2;
    unsigned short* qbf  = (unsigned short*)w; w += R * 256 * 2;
    unsigned short* WTin = (unsigned short*)w; w += (size_t)256 * 512 * 2;
    unsigned short* WTq  = (unsigned short*)w; w += (size_t)256 * 256 * 2;
    unsigned short* WTk  = (unsigned short*)w; w += (size_t)256 * 256 * 2;
    unsigned short* Xbf  = (unsigned short*)w; w += R * 256 * 2;
    unsigned short* Qbf  = (unsigned short*)w; w += R * 256 * 2;
    unsigned short* Kbf  = (unsigned short*)w; w += R * 256 * 2;
    float* Wvw  = (float*)w; w += 2048 * 4;
    float* Vw   = (float*)w; w += R * 8 * 4;
    float* bvw  = (float*)w; w += 256;          // 8 floats + pad
    float* dent = (float*)w; w += (size_t)32 * SEQ * 4;           // 64 KB
    float* denr = (float*)w; w += (size_t)32 * SEQ * 4;           // 64 KB

    float* logits = (float*)d_out;
    float* attnp  = (float*)d_out + 16384;

    // L1: prep || wcombo (+logits init) || dent/denr
    fused_prep_kernel<<<dim3(5705), dim3(256), 0, stream>>>(
        item_inputs, label_inputs, item_ids, emb,
        W_in, Wq, Wk, Wv, Wout, bv, bout, rel, tsp,
        Abig, qbf, WTin, WTq, WTk, Wvw, bvw, logits, dent, denr);

    // L2: X-GEMM || Q-GEMM
    gemmA_kernel<<<dim3(256, 2, 2), dim3(256), 0, stream>>>(
        Abig, WTin, b_in, Xbf, qbf, WTq, bq, Qbf);

    // L3: K-GEMM || Vw
    gemmB_kernel<<<dim3(256, 2, 2), dim3(256), 0, stream>>>(
        Xbf, WTk, bk, Kbf, Wvw, bvw, Vw);

    // L4: fully fused attention (scores+den+blend+write+logits)
    attnW_kernel<<<dim3(8192), dim3(256), 0, stream>>>(
        Qbf, Kbf, Vw, rel, tsp, dent, denr, l1, l2, logits, attnp);
}

// Round 13
// 144.927 us; speedup vs baseline: 2.7027x; 1.0606x over previous
//
#include <hip/hip_runtime.h>
#include <hip/hip_bf16.h>

#define SEQ 512
#define EMB 256
#define NHEAD 8
#define HD 32

using bf16x8 = __attribute__((ext_vector_type(8))) short;
using f32x4  = __attribute__((ext_vector_type(4))) float;

static __device__ __forceinline__ unsigned short f2bf(float x) {
    union { float f; unsigned int u; } v; v.f = x;
    unsigned int r = v.u + 0x7FFFu + ((v.u >> 16) & 1u);
    return (unsigned short)(r >> 16);
}
static __device__ __forceinline__ float bf2f(unsigned short v) {
    union { unsigned int u; float f; } w; w.u = ((unsigned int)v) << 16; return w.f;
}

// ---------------- L1: dentr (heavy, first) || prep || wcombo
// grid 6217: [0,1024) dentr; [1024,5120) prep; [5120,6217) wcombo
__global__ __launch_bounds__(256) void fused_prep_kernel(
    const int* __restrict__ item_inputs,
    const int* __restrict__ label_inputs,
    const int* __restrict__ item_ids,
    const float* __restrict__ embeds,
    const float* __restrict__ W_in,
    const float* __restrict__ Wq,
    const float* __restrict__ Wk,
    const float* __restrict__ Wv,
    const float* __restrict__ Wout,
    const float* __restrict__ bv,
    const float* __restrict__ bout,
    const float* __restrict__ rel,
    const float* __restrict__ tsp,
    unsigned short* __restrict__ Abig,   // 16384 x 512 bf16
    unsigned short* __restrict__ qbf,    // 16384 x 256 bf16
    unsigned short* __restrict__ WTin,   // 256 x 512
    unsigned short* __restrict__ WTq,    // 256 x 256
    unsigned short* __restrict__ WTk,    // 256 x 256
    float* __restrict__ Wvw,             // 256 x 8
    float* __restrict__ bvw,             // 8
    float* __restrict__ logits,          // init to bout
    float* __restrict__ dent,            // [32][512] written directly
    float* __restrict__ denr)            // [32][512] written directly
{
    const int bid = blockIdx.x;
    const int t = threadIdx.x;

    if (bid < 1024) {            // ---- dentr: 16-row strips, heavy first ----
        const int b = bid >> 5;
        const int s16 = 31 - (bid & 31);   // heavy strips first
        const int q0 = s16 * 16;
        const int row = t >> 4;            // 16 rows per block
        const int lane16 = t & 15;
        const int qrow = q0 + row;
        const size_t base = ((size_t)(b * SEQ) + qrow) * SEQ;
        float dt = 0.f, dr = 0.f;
        for (int k4 = lane16 * 4; k4 <= qrow; k4 += 64) {
            float4 tv4 = *(const float4*)(tsp + base + k4);
            float4 rv4 = *(const float4*)(rel + base + k4);
            const float* tvp = &tv4.x;
            const float* rvp = &rv4.x;
            #pragma unroll
            for (int j = 0; j < 4; j++) {
                const bool va = (k4 + j) <= qrow;
                dt += va ? __expf(__expf(-fabsf(tvp[j]))) : 0.f;
                dr += (va && rvp[j] != 0.f) ? __expf(rvp[j]) : 0.f;
            }
        }
        dt += __shfl_xor(dt, 1); dt += __shfl_xor(dt, 2);
        dt += __shfl_xor(dt, 4); dt += __shfl_xor(dt, 8);
        dr += __shfl_xor(dr, 1); dr += __shfl_xor(dr, 2);
        dr += __shfl_xor(dr, 4); dr += __shfl_xor(dr, 8);
        if (lane16 == 0) {
            dent[b * SEQ + qrow] = dt;
            denr[b * SEQ + qrow] = dr;
        }
    } else if (bid < 5120) {     // ---- prep ----
        int r = (bid - 1024) * 4 + (t >> 6);
        int j = (t & 63) * 4;
        int item = item_inputs[r];
        int lab  = label_inputs[r];
        int qid  = item_ids[r];
        float4 e4 = *(const float4*)(embeds + (size_t)item * EMB + j);
        ushort4 on  = make_ushort4(f2bf(e4.x), f2bf(e4.y), f2bf(e4.z), f2bf(e4.w));
        ushort4 off = make_ushort4(0, 0, 0, 0);
        *(ushort4*)(Abig + (size_t)r * 512 + j)       = lab ? on : off;
        *(ushort4*)(Abig + (size_t)r * 512 + 256 + j) = lab ? off : on;
        float4 q4 = *(const float4*)(embeds + (size_t)qid * EMB + j);
        *(ushort4*)(qbf + (size_t)r * 256 + j) =
            make_ushort4(f2bf(q4.x), f2bf(q4.y), f2bf(q4.z), f2bf(q4.w));
    } else {                     // ---- wcombo ----
        int idx = (bid - 5120) * 256 + t;
        if (idx < 131072) {                       // WTin[n][k] = W_in[k][n], K=512
            int n = idx >> 9, k = idx & 511;
            WTin[idx] = f2bf(W_in[(size_t)k * 256 + n]);
        } else if (idx < 196608) {                // WTq
            int i = idx - 131072;
            int n = i >> 8, k = i & 255;
            WTq[i] = f2bf(Wq[(size_t)k * 256 + n]);
        } else if (idx < 262144) {                // WTk
            int i = idx - 196608;
            int n = i >> 8, k = i & 255;
            WTk[i] = f2bf(Wk[(size_t)k * 256 + n]);
        } else if (idx < 264192) {                // Wvw
            int i = idx - 262144;
            int c = i >> 3, h = i & 7;
            float s = 0.f;
            #pragma unroll
            for (int d = 0; d < 32; d++)
                s += Wv[(size_t)c * 256 + h * 32 + d] * Wout[h * 32 + d];
            Wvw[i] = s;
        } else if (idx < 264200) {                // bvw
            int h = idx - 264192;
            float s = 0.f;
            #pragma unroll
            for (int d = 0; d < 32; d++) s += bv[h * 32 + d] * Wout[h * 32 + d];
            bvw[h] = s;
        } else if (idx < 280584) {                // logits init = bout
            logits[idx - 264200] = bout[0];
        }
    }
}

// ---------------- MFMA GEMM body: C(M x 256) = A(M x KDIM) * BT^T + bias
template<int KDIM, int RELU, int OUTBF>
static __device__ __forceinline__ void gemm_body(
    const unsigned short* __restrict__ A,
    const unsigned short* __restrict__ BT,
    const float* __restrict__ bias,
    void* __restrict__ Cout, float scale)
{
    __shared__ unsigned short As[64][40];
    __shared__ unsigned short Bs[128][40];
    const int t = threadIdx.x;
    const int row0 = blockIdx.x * 64;
    const int col0 = blockIdx.y * 128;
    const int wid = t >> 6, lane = t & 63;
    const int wm = wid & 1, wn = wid >> 1;
    const int lg = lane >> 4, l15 = lane & 15;

    f32x4 acc[2][4];
    #pragma unroll
    for (int i = 0; i < 2; i++)
        #pragma unroll
        for (int j = 0; j < 4; j++) acc[i][j] = (f32x4){0.f, 0.f, 0.f, 0.f};

    const int arow = t >> 2, achk = t & 3;
    const int brow = t >> 1, bhalf = t & 1;

    for (int k0 = 0; k0 < KDIM; k0 += 32) {
        __syncthreads();
        *(uint4*)(&As[arow][achk * 8]) =
            *(const uint4*)(A + (size_t)(row0 + arow) * KDIM + k0 + achk * 8);
        const unsigned short* bsrc = BT + (size_t)(col0 + brow) * KDIM + k0 + bhalf * 16;
        *(uint4*)(&Bs[brow][bhalf * 16])     = *(const uint4*)(bsrc);
        *(uint4*)(&Bs[brow][bhalf * 16 + 8]) = *(const uint4*)(bsrc + 8);
        __syncthreads();
        bf16x8 af[2], bfr[4];
        #pragma unroll
        for (int fm = 0; fm < 2; fm++)
            af[fm] = *(const bf16x8*)(&As[wm * 32 + fm * 16 + l15][lg * 8]);
        #pragma unroll
        for (int fn = 0; fn < 4; fn++)
            bfr[fn] = *(const bf16x8*)(&Bs[wn * 64 + fn * 16 + l15][lg * 8]);
        #pragma unroll
        for (int fm = 0; fm < 2; fm++)
            #pragma unroll
            for (int fn = 0; fn < 4; fn++)
                acc[fm][fn] = __builtin_amdgcn_mfma_f32_16x16x32_bf16(
                    af[fm], bfr[fn], acc[fm][fn], 0, 0, 0);
    }
    #pragma unroll
    for (int fm = 0; fm < 2; fm++)
        #pragma unroll
        for (int fn = 0; fn < 4; fn++) {
            int col = col0 + wn * 64 + fn * 16 + l15;
            float bvv = bias[col];
            #pragma unroll
            for (int r = 0; r < 4; r++) {
                int row = row0 + wm * 32 + fm * 16 + lg * 4 + r;
                float v = acc[fm][fn][r] + bvv;
                if (RELU) v = fmaxf(v, 0.f);
                v *= scale;
                if (OUTBF) ((unsigned short*)Cout)[(size_t)row * 256 + col] = f2bf(v);
                else       ((float*)Cout)[(size_t)row * 256 + col] = v;
            }
        }
}

// ---------------- L2: X-GEMM (K=512, relu) || Q-GEMM (independent) via z
__global__ __launch_bounds__(256, 2) void gemmA_kernel(
    const unsigned short* __restrict__ Abig,
    const unsigned short* __restrict__ WTin,
    const float* __restrict__ b_in,
    unsigned short* __restrict__ Xbf,
    const unsigned short* __restrict__ qbf,
    const unsigned short* __restrict__ WTq,
    const float* __restrict__ bq,
    unsigned short* __restrict__ Qbf)
{
    if (blockIdx.z == 0)
        gemm_body<512, 1, 1>(Abig, WTin, b_in, (void*)Xbf, 1.0f);
    else
        gemm_body<256, 0, 1>(qbf, WTq, bq, (void*)Qbf, 0.17677669529663687f);
}

// ---------------- Vw body: Vw[row][h] = X[row]·Wvw[:,h] + bvw[h]
static __device__ __forceinline__ void vw_body(
    const unsigned short* __restrict__ Xbf,
    const float* __restrict__ Wvw,
    const float* __restrict__ bvw,
    float* __restrict__ Vw)
{
    __shared__ float sW[2048];
    __shared__ float sb[8];
    int t = threadIdx.x;
    #pragma unroll
    for (int i = 0; i < 8; i++) sW[i * 256 + t] = Wvw[i * 256 + t];
    if (t < 8) sb[t] = bvw[t];
    __syncthreads();
    int row = blockIdx.x * 256 + t;
    float acc[8];
    #pragma unroll
    for (int h = 0; h < 8; h++) acc[h] = sb[h];
    for (int d0 = 0; d0 < 32; d0++) {
        bf16x8 x = *(const bf16x8*)(Xbf + (size_t)row * 256 + d0 * 8);
        #pragma unroll
        for (int j = 0; j < 8; j++) {
            float xf = bf2f((unsigned short)x[j]);
            #pragma unroll
            for (int h = 0; h < 8; h++) acc[h] += xf * sW[(d0 * 8 + j) * 8 + h];
        }
    }
    *(float4*)(Vw + (size_t)row * 8)     = make_float4(acc[0], acc[1], acc[2], acc[3]);
    *(float4*)(Vw + (size_t)row * 8 + 4) = make_float4(acc[4], acc[5], acc[6], acc[7]);
}

// ---------------- L3: K-GEMM || Vw via z
__global__ __launch_bounds__(256, 2) void gemmB_kernel(
    const unsigned short* __restrict__ Xbf,
    const unsigned short* __restrict__ WTk,
    const float* __restrict__ bk,
    unsigned short* __restrict__ Kbf,
    const float* __restrict__ Wvw,
    const float* __restrict__ bvw,
    float* __restrict__ Vw)
{
    if (blockIdx.z == 0) {
        gemm_body<256, 0, 1>(Xbf, WTk, bk, (void*)Kbf, 1.0f);
    } else {
        if (blockIdx.x >= 64 || blockIdx.y != 0) return;
        vw_body(Xbf, Wvw, bvw, Vw);
    }
}

// ---------------- L4: attnW v6 — fused, bf16 sP for 8 blocks/CU occupancy
// grid 8192: id -> strip heavy-first (32) x b (32) x h (8); 256 threads = 4 waves
__global__ __launch_bounds__(256, 8) void attnW_kernel(
    const unsigned short* __restrict__ Qbf,
    const unsigned short* __restrict__ Kbf,
    const float* __restrict__ Vw,
    const float* __restrict__ rel,
    const float* __restrict__ tsp,
    const float* __restrict__ dent,
    const float* __restrict__ denr,
    const float* __restrict__ pl1,
    const float* __restrict__ pl2,
    float* __restrict__ logits,
    float* __restrict__ attn)
{
    __shared__ unsigned short sP[16][520];  // exp(score) bf16; 2-way alias max (free)
    __shared__ float sVw[512];
    __shared__ float sden[4][16];

    const int t = threadIdx.x;
    const int id = blockIdx.x;
    const int qt16 = 31 - (id >> 8);      // heavy strips dispatched first
    const int b = (id >> 3) & 31;
    const int h = id & 7;                 // h innermost: 8 neighbors share rel/ts rows
    const int q0 = qt16 * 16;
    const int qmax = q0 + 15;

    const int w = t >> 6, lane = t & 63;
    const int l15 = lane & 15, lg = lane >> 4;

    const float l1 = pl1[0], l2 = pl2[0];
    const float cp = (1.f - l1) * (1.f - l2);
    const float ct = (1.f - l1) * l2;
    const float cr = l1;

    // stage Vw column h for this b
    sVw[t]       = Vw[((size_t)(b * SEQ) + t) * 8 + h];
    sVw[256 + t] = Vw[((size_t)(b * SEQ) + 256 + t) * 8 + h];

    // Q fragment: rows q0+l15, dims h*32 + lg*8
    bf16x8 aq = *(const bf16x8*)(Qbf + (size_t)(b * SEQ + q0 + l15) * EMB + h * 32 + lg * 8);

    // ---- phase 1: MFMA scores -> exp -> sP (bf16); per-row den partials in f32 ----
    float dp[4] = {0.f, 0.f, 0.f, 0.f};
    #pragma unroll
    for (int ki = 0; ki < 4; ki++) {
        const int kt = w + ki * 4;        // wave-uniform tile index 0..15
        const int k0 = kt * 32;
        if (k0 <= qmax) {
            #pragma unroll
            for (int nf = 0; nf < 2; nf++) {
                const int kcol = k0 + nf * 16 + l15;
                bf16x8 bk = *(const bf16x8*)(Kbf +
                    (size_t)(b * SEQ + kcol) * EMB + h * 32 + lg * 8);
                f32x4 am = __builtin_amdgcn_mfma_f32_16x16x32_bf16(
                    aq, bk, (f32x4){0.f, 0.f, 0.f, 0.f}, 0, 0, 0);
                #pragma unroll
                for (int r = 0; r < 4; r++) {
                    const int qloc = lg * 4 + r;
                    float e = (kcol <= q0 + qloc) ? __expf(am[r]) : 0.f;
                    sP[qloc][kcol] = f2bf(e);
                    dp[r] += e;
                }
            }
        } else {
            #pragma unroll
            for (int nf = 0; nf < 2; nf++)
                #pragma unroll
                for (int r = 0; r < 4; r++)
                    sP[lg * 4 + r][k0 + nf * 16 + l15] = 0;
        }
    }
    #pragma unroll
    for (int r = 0; r < 4; r++) {
        float v = dp[r];
        v += __shfl_xor(v, 1); v += __shfl_xor(v, 2);
        v += __shfl_xor(v, 4); v += __shfl_xor(v, 8);
        if (l15 == 0) sden[w][lg * 4 + r] = v;
    }
    __syncthreads();

    // ---- phase 2: normalize + blend + nt write + logits ----
    const int wrow = t >> 4;
    const int wcol = (t & 15) * 4;
    const int qrow_w = q0 + wrow;
    const float den = sden[0][wrow] + sden[1][wrow] + sden[2][wrow] + sden[3][wrow];
    const float cpinv = cp / den;         // den>0: diagonal always valid
    const float dtv = dent[b * SEQ + qrow_w];
    const float drv = denr[b * SEQ + qrow_w];
    const float ctt = ct / dtv;
    const float crr = drv > 0.f ? cr / drv : 0.f;

    float* arow = attn + ((size_t)((b * NHEAD + h) * SEQ) + qrow_w) * SEQ;
    const size_t rbase = ((size_t)(b * SEQ) + qrow_w) * SEQ;
    const f32x4 z4 = (f32x4){0.f, 0.f, 0.f, 0.f};
    float plog = 0.f;

    #pragma unroll
    for (int s = 0; s < 8; s++) {
        const int c = wcol + s * 64;
        f32x4 o;
        if (c > qrow_w) {
            o = z4;
        } else {
            float4 tv4 = *(const float4*)(tsp + rbase + c);
            float4 rv4 = *(const float4*)(rel + rbase + c);
            ushort4 p4 = *(const ushort4*)(&sP[wrow][c]);
            const float* tvp = &tv4.x;
            const float* rvp = &rv4.x;
            const unsigned short* pp = &p4.x;
            #pragma unroll
            for (int j = 0; j < 4; j++) {
                const bool va = (c + j) <= qrow_w;
                float e_t = va ? __expf(__expf(-fabsf(tvp[j]))) * ctt : 0.f;
                float e_r = (va && rvp[j] != 0.f) ? __expf(rvp[j]) * crr : 0.f;
                float a = fmaf(bf2f(pp[j]), cpinv, e_t + e_r);  // sP=0 if invalid
                a = va ? a : 0.f;
                o[j] = a;
                plog = fmaf(a, sVw[c + j], plog);
            }
        }
        __builtin_nontemporal_store(o, (f32x4*)(arow + c));
    }

    // per-row logits: reduce over the 16 col-lanes, one atomic per row
    plog += __shfl_xor(plog, 1); plog += __shfl_xor(plog, 2);
    plog += __shfl_xor(plog, 4); plog += __shfl_xor(plog, 8);
    if ((t & 15) == 0)
        atomicAdd(&logits[b * SEQ + qrow_w], plog);
}

// ---------------- host launch ----------------
extern "C" void kernel_launch(void* const* d_in, const int* in_sizes, int n_in,
                              void* d_out, int out_size, void* d_ws, size_t ws_size,
                              hipStream_t stream)
{
    (void)in_sizes; (void)n_in; (void)out_size; (void)ws_size;
    const int*   item_inputs  = (const int*)d_in[0];
    const int*   label_inputs = (const int*)d_in[1];
    const int*   item_ids     = (const int*)d_in[2];
    const float* rel   = (const float*)d_in[3];
    const float* tsp   = (const float*)d_in[4];
    const float* emb   = (const float*)d_in[5];
    const float* W_in  = (const float*)d_in[6];
    const float* b_in  = (const float*)d_in[7];
    const float* Wq    = (const float*)d_in[8];
    const float* bq    = (const float*)d_in[9];
    const float* Wk    = (const float*)d_in[10];
    const float* bk    = (const float*)d_in[11];
    const float* Wv    = (const float*)d_in[12];
    const float* bv    = (const float*)d_in[13];
    const float* Wout  = (const float*)d_in[14];
    const float* bout  = (const float*)d_in[15];
    const float* l1    = (const float*)d_in[16];
    const float* l2    = (const float*)d_in[17];

    const size_t R = 16384;
    char* w = (char*)d_ws;
    unsigned short* Abig = (unsigned short*)w; w += R * 512 * 2;
    unsigned short* qbf  = (unsigned short*)w; w += R * 256 * 2;
    unsigned short* WTin = (unsigned short*)w; w += (size_t)256 * 512 * 2;
    unsigned short* WTq  = (unsigned short*)w; w += (size_t)256 * 256 * 2;
    unsigned short* WTk  = (unsigned short*)w; w += (size_t)256 * 256 * 2;
    unsigned short* Xbf  = (unsigned short*)w; w += R * 256 * 2;
    unsigned short* Qbf  = (unsigned short*)w; w += R * 256 * 2;
    unsigned short* Kbf  = (unsigned short*)w; w += R * 256 * 2;
    float* Wvw  = (float*)w; w += 2048 * 4;
    float* Vw   = (float*)w; w += R * 8 * 4;
    float* bvw  = (float*)w; w += 256;          // 8 floats + pad
    float* dent = (float*)w; w += (size_t)32 * SEQ * 4;           // 64 KB
    float* denr = (float*)w; w += (size_t)32 * SEQ * 4;           // 64 KB

    float* logits = (float*)d_out;
    float* attnp  = (float*)d_out + 16384;

    // L1: dentr (first, heavy) || prep || wcombo (+logits init)
    fused_prep_kernel<<<dim3(6217), dim3(256), 0, stream>>>(
        item_inputs, label_inputs, item_ids, emb,
        W_in, Wq, Wk, Wv, Wout, bv, bout, rel, tsp,
        Abig, qbf, WTin, WTq, WTk, Wvw, bvw, logits, dent, denr);

    // L2: X-GEMM || Q-GEMM
    gemmA_kernel<<<dim3(256, 2, 2), dim3(256), 0, stream>>>(
        Abig, WTin, b_in, Xbf, qbf, WTq, bq, Qbf);

    // L3: K-GEMM || Vw
    gemmB_kernel<<<dim3(256, 2, 2), dim3(256), 0, stream>>>(
        Xbf, WTk, bk, Kbf, Wvw, bvw, Vw);

    // L4: fully fused attention (scores+den+blend+write+logits)
    attnW_kernel<<<dim3(8192), dim3(256), 0, stream>>>(
        Qbf, Kbf, Vw, rel, tsp, dent, denr, l1, l2, logits, attnp);
}